// Round 4
// baseline (897.422 us; speedup 1.0000x reference)
//
#include <hip/hip_runtime.h>

#define EPS 1e-5f
#define NBLK 768

typedef _Float16 f16x8 __attribute__((ext_vector_type(8)));
typedef _Float16 f16x4 __attribute__((ext_vector_type(4)));
typedef float f32x4 __attribute__((ext_vector_type(4)));

// ---- workspace layout (float offsets) ----
#define XT_OFF    0u          // fp32 256*1024
#define ACT1_OFF  262144u     // f16 196*1024*16
#define ACT2_OFF  1867776u    // f16 144*1024*32
#define ACT3_OFF  4227072u    // f16 100*1024*64
#define W2H_OFF   7503872u    // f16 144*5*32*32
#define W3H_OFF   7872512u    // f16 100*9*64*32
#define P1_OFF    8794112u    // fp32 2*16*3136
#define P2_OFF    8894464u    // fp32 2*32*4608
#define P3_OFF    9189376u    // fp32 2*64*3200
#define FP_OFF    9598976u    // fp32 200*10*1024
#define PRM_OFF   11646976u   // fp32 224
#define ACH_OFF   11647200u   // f16 224 (112 floats)
#define BAR_OFF   11647312u   // int 7*1056 = 7392

// ---------------- prep: weight repack (LDS-staged), x transpose, barrier zero ----------------
__global__ __launch_bounds__(256) void k_prep(const float* __restrict__ x,
                                              const float* __restrict__ W2,
                                              const float* __restrict__ W3,
                                              float* __restrict__ xT,
                                              _Float16* __restrict__ W2h,
                                              _Float16* __restrict__ W3h,
                                              int* __restrict__ bar) {
    __shared__ _Float16 sh[18432];
    __shared__ float tile[16][17];
    int blk = blockIdx.x, tid = threadIdx.x;
    if (blk < 144) {                    // W2 -> W2h [p][t5][o32][k32], pos-pair packed, zero pad
        int p = blk;
        for (int i = tid; i < 5120; i += 256) sh[i] = (_Float16)0.f;
        __syncthreads();
        for (int s = 0; s < 2; s++) {
            int seg = tid + s * 256;    // o*16+c
            int o = seg >> 4, c = seg & 15;
            const float* src = W2 + (size_t)seg * 1296 + p * 9;
#pragma unroll
            for (int pos = 0; pos < 9; pos++) {
                int d = (pos >> 1) * 1024 + o * 32 + (pos & 1) * 16 + c;
                sh[d] = (_Float16)src[pos];
            }
        }
        __syncthreads();
        const int* shi = (const int*)sh;
        int* dst = (int*)(W2h + (size_t)p * 5120);
        for (int i = tid; i < 2560; i += 256) dst[i] = shi[i];
    } else if (blk < 244) {             // W3 -> W3h [p][pos9][o64][c32]
        int p = blk - 144;
        for (int s = 0; s < 8; s++) {
            int seg = tid + s * 256;    // o*32+c
            const float* src = W3 + (size_t)seg * 900 + p * 9;
#pragma unroll
            for (int pos = 0; pos < 9; pos++) sh[pos * 2048 + seg] = (_Float16)src[pos];
        }
        __syncthreads();
        const int* shi = (const int*)sh;
        int* dst = (int*)(W3h + (size_t)p * 18432);
        for (int i = tid; i < 9216; i += 256) dst[i] = shi[i];
    } else if (blk < 1268) {            // x (1024,256) -> xT (256,1024)
        int q = blk - 244;
        int bx = q & 15, by = q >> 4;
        int tx = tid & 15, ty = tid >> 4;
        tile[ty][tx] = x[(by * 16 + ty) * 256 + bx * 16 + tx];
        __syncthreads();
        xT[(bx * 16 + ty) * 1024 + by * 16 + tx] = tile[tx][ty];
    } else {
        for (int i = tid; i < 7392; i += 256) bar[i] = 0;
    }
}

// ---------------- two-level grid barrier: 64 padded leaves -> root -> flag ----------------
__device__ __forceinline__ void gridbar(int* bar, int k) {
    __syncthreads();
    int* base = bar + k * 1056;
    if (threadIdx.x == 0) {
        __threadfence();
        int leaf = blockIdx.x & 63;
        int prev = __hip_atomic_fetch_add(base + leaf * 16, 1, __ATOMIC_ACQ_REL, __HIP_MEMORY_SCOPE_AGENT);
        if (prev == (NBLK / 64) - 1) {
            int r = __hip_atomic_fetch_add(base + 1024, 1, __ATOMIC_ACQ_REL, __HIP_MEMORY_SCOPE_AGENT);
            if (r == 63) __hip_atomic_store(base + 1040, 1, __ATOMIC_RELEASE, __HIP_MEMORY_SCOPE_AGENT);
        }
        while (__hip_atomic_load(base + 1040, __ATOMIC_ACQUIRE, __HIP_MEMORY_SCOPE_AGENT) == 0)
            __builtin_amdgcn_s_sleep(8);
        __threadfence();
    }
    __syncthreads();
}

__device__ void stats_phase(const float* __restrict__ part, int nwaves,
                            const float* __restrict__ g, const float* __restrict__ be,
                            float* __restrict__ a, float* __restrict__ c,
                            _Float16* achA, _Float16* achC, int ch, float invN,
                            float* shf) {
    int tid = threadIdx.x;
    const float* ps = part + (size_t)(2 * ch) * nwaves;
    const float* pq = part + (size_t)(2 * ch + 1) * nwaves;
    float s = 0.f, q = 0.f;
    for (int w = tid; w < nwaves; w += 256) { s += ps[w]; q += pq[w]; }
#pragma unroll
    for (int d = 32; d; d >>= 1) { s += __shfl_down(s, d); q += __shfl_down(q, d); }
    if ((tid & 63) == 0) { shf[tid >> 6] = s; shf[4 + (tid >> 6)] = q; }
    __syncthreads();
    if (tid == 0) {
        s = shf[0] + shf[1] + shf[2] + shf[3];
        q = shf[4] + shf[5] + shf[6] + shf[7];
        float m = s * invN;
        float v = q * invN - m * m;
        float r = rsqrtf(v + EPS);
        float av = g[ch] * r, cv = be[ch] - m * av;
        a[ch] = av; c[ch] = cv;
        if (achA) { achA[ch] = (_Float16)av; achC[ch] = (_Float16)cv; }
    }
}

// ---------------- the whole net: 8 phases, 7 grid barriers ----------------
__global__ __launch_bounds__(256, 3) void k_fused(
    const float* __restrict__ xT, const float* __restrict__ W1, const float* __restrict__ b1v,
    const float* __restrict__ g1, const float* __restrict__ be1,
    const _Float16* __restrict__ W2h, const float* __restrict__ b2v,
    const float* __restrict__ g2, const float* __restrict__ be2,
    const _Float16* __restrict__ W3h, const float* __restrict__ b3v,
    const float* __restrict__ g3, const float* __restrict__ be3,
    const float* __restrict__ fcW, const float* __restrict__ fcb,
    _Float16* __restrict__ act1h, _Float16* __restrict__ act2h, _Float16* __restrict__ act3h,
    float* __restrict__ p1, float* __restrict__ p2, float* __restrict__ p3,
    float* __restrict__ fpart, float* __restrict__ prm, _Float16* __restrict__ ach,
    float* __restrict__ out, int* __restrict__ bar) {
    __shared__ float shf[448];
    int blk = blockIdx.x, tid = threadIdx.x;
    int wv = tid >> 6, lane = tid & 63;
    int n = lane & 15, quad = lane >> 4;

    // ---- P0: LC1 (fp32 VALU) ----
    for (int t = blk; t < 784; t += NBLK) {
        int p = t % 196, bch = t / 196;
        int i = p / 14, j = p % 14;
        __syncthreads();
        if (tid < 144) { int o = tid / 9, k = tid % 9; shf[tid] = W1[(o * 196 + p) * 9 + k]; }
        if (tid < 16) shf[144 + tid] = b1v[tid * 196 + p];
        __syncthreads();
        int b = bch * 256 + tid;
        float xv[9];
#pragma unroll
        for (int di = 0; di < 3; di++)
#pragma unroll
            for (int dj = 0; dj < 3; dj++)
                xv[di * 3 + dj] = xT[((i + di) * 16 + (j + dj)) * 1024 + b];
        float accv[16];
#pragma unroll
        for (int o = 0; o < 16; o++) {
            float acc = shf[144 + o];
#pragma unroll
            for (int k = 0; k < 9; k++) acc += shf[o * 9 + k] * xv[k];
            accv[o] = acc;
        }
        f16x8 lo, hi;
#pragma unroll
        for (int e = 0; e < 8; e++) { lo[e] = (_Float16)accv[e]; hi[e] = (_Float16)accv[8 + e]; }
        _Float16* dst = act1h + ((size_t)(p * 1024 + b)) * 16;
        *(f16x8*)dst = lo;
        *(f16x8*)(dst + 8) = hi;
        int w = (bch * 196 + p) * 4 + wv;
#pragma unroll
        for (int o = 0; o < 16; o++) {
            float s = accv[o], q = accv[o] * accv[o];
#pragma unroll
            for (int d = 32; d; d >>= 1) { s += __shfl_down(s, d); q += __shfl_down(q, d); }
            if (lane == 0) { p1[(2 * o) * 3136 + w] = s; p1[(2 * o + 1) * 3136 + w] = q; }
        }
    }
    gridbar(bar, 0);
    // ---- P1: stats1 (blocks 752..767) ----
    if (blk >= 752)
        stats_phase(p1, 3136, g1, be1, prm, prm + 16, ach, ach + 16, blk - 752,
                    1.f / (1024.f * 196.f), shf);
    gridbar(bar, 1);
    // ---- P2: LC2 MFMA ----
    for (int t = blk; t < 1152; t += NBLK) {
        int p = t >> 3, bg = t & 7;
        int i = p / 12, j = p % 12;
        int bbase = bg * 128 + wv * 32;
        f16x8 a8 = *(const f16x8*)(ach + (quad & 1) * 8);
        f16x8 c8 = *(const f16x8*)(ach + 16 + (quad & 1) * 8);
        f32x4 acc[2][2] = {};
#pragma unroll
        for (int tt = 0; tt < 5; tt++) {
            int pos0 = 2 * tt, pos1 = (2 * tt + 1 < 9) ? 2 * tt + 1 : 8;
            int mypos = (quad >> 1) ? pos1 : pos0;
            int ip = (i + mypos / 3) * 14 + (j + mypos % 3);
            f16x8 bfr[2];
#pragma unroll
            for (int nt = 0; nt < 2; nt++) {
                f16x8 x = *(const f16x8*)(act1h + ((size_t)(ip * 1024 + bbase + nt * 16 + n)) * 16 + (quad & 1) * 8);
#pragma unroll
                for (int e = 0; e < 8; e++) {
                    _Float16 v = x[e] * a8[e] + c8[e];
                    x[e] = v > (_Float16)0.f ? v : (_Float16)0.f;
                }
                bfr[nt] = x;
            }
            f16x8 afr[2];
#pragma unroll
            for (int ot = 0; ot < 2; ot++)
                afr[ot] = *(const f16x8*)(W2h + ((size_t)((p * 5 + tt) * 32 + ot * 16 + n)) * 32 + quad * 8);
#pragma unroll
            for (int ot = 0; ot < 2; ot++)
#pragma unroll
                for (int nt = 0; nt < 2; nt++)
                    acc[ot][nt] = __builtin_amdgcn_mfma_f32_16x16x32_f16(afr[ot], bfr[nt], acc[ot][nt], 0, 0, 0);
        }
        float s[8] = {}, q[8] = {};
#pragma unroll
        for (int ot = 0; ot < 2; ot++) {
            float bias[4];
#pragma unroll
            for (int r = 0; r < 4; r++) bias[r] = b2v[(ot * 16 + quad * 4 + r) * 144 + p];
#pragma unroll
            for (int nt = 0; nt < 2; nt++) {
                int b = bbase + nt * 16 + n;
                f16x4 st;
#pragma unroll
                for (int r = 0; r < 4; r++) {
                    float v = acc[ot][nt][r] + bias[r];
                    st[r] = (_Float16)v;
                    s[ot * 4 + r] += v; q[ot * 4 + r] += v * v;
                }
                *(f16x4*)(act2h + ((size_t)(p * 1024 + b)) * 32 + ot * 16 + quad * 4) = st;
            }
        }
        int w = t * 4 + wv;
#pragma unroll
        for (int u = 0; u < 8; u++) {
            float ss = s[u], qq = q[u];
#pragma unroll
            for (int d = 8; d; d >>= 1) { ss += __shfl_down(ss, d); qq += __shfl_down(qq, d); }
            if (n == 0) {
                int o = (u >> 2) * 16 + quad * 4 + (u & 3);
                p2[(2 * o) * 4608 + w] = ss; p2[(2 * o + 1) * 4608 + w] = qq;
            }
        }
    }
    gridbar(bar, 2);
    // ---- P3: stats2 (blocks 736..767) ----
    if (blk >= 736)
        stats_phase(p2, 4608, g2, be2, prm + 32, prm + 64, ach + 32, ach + 64, blk - 736,
                    1.f / (1024.f * 144.f), shf);
    gridbar(bar, 3);
    // ---- P4: LC3 MFMA ----
    for (int t = blk; t < 800; t += NBLK) {
        int p = t >> 3, bg = t & 7;
        int i = p / 10, j = p % 10;
        int bbase = bg * 128 + wv * 32;
        f16x8 a8 = *(const f16x8*)(ach + 32 + quad * 8);
        f16x8 c8 = *(const f16x8*)(ach + 64 + quad * 8);
        f32x4 acc[4][2] = {};
#pragma unroll
        for (int pos = 0; pos < 9; pos++) {
            int ip = (i + pos / 3) * 12 + (j + pos % 3);
            f16x8 bfr[2];
#pragma unroll
            for (int nt = 0; nt < 2; nt++) {
                f16x8 x = *(const f16x8*)(act2h + ((size_t)(ip * 1024 + bbase + nt * 16 + n)) * 32 + quad * 8);
#pragma unroll
                for (int e = 0; e < 8; e++) {
                    _Float16 v = x[e] * a8[e] + c8[e];
                    x[e] = v > (_Float16)0.f ? v : (_Float16)0.f;
                }
                bfr[nt] = x;
            }
            f16x8 afr[4];
#pragma unroll
            for (int ot = 0; ot < 4; ot++)
                afr[ot] = *(const f16x8*)(W3h + ((size_t)((p * 9 + pos) * 64 + ot * 16 + n)) * 32 + quad * 8);
#pragma unroll
            for (int ot = 0; ot < 4; ot++)
#pragma unroll
                for (int nt = 0; nt < 2; nt++)
                    acc[ot][nt] = __builtin_amdgcn_mfma_f32_16x16x32_f16(afr[ot], bfr[nt], acc[ot][nt], 0, 0, 0);
        }
        float s[16] = {}, q[16] = {};
#pragma unroll
        for (int ot = 0; ot < 4; ot++) {
            float bias[4];
#pragma unroll
            for (int r = 0; r < 4; r++) bias[r] = b3v[(ot * 16 + quad * 4 + r) * 100 + p];
#pragma unroll
            for (int nt = 0; nt < 2; nt++) {
                int b = bbase + nt * 16 + n;
                f16x4 st;
#pragma unroll
                for (int r = 0; r < 4; r++) {
                    float v = acc[ot][nt][r] + bias[r];
                    st[r] = (_Float16)v;
                    s[ot * 4 + r] += v; q[ot * 4 + r] += v * v;
                }
                *(f16x4*)(act3h + ((size_t)(p * 1024 + b)) * 64 + ot * 16 + quad * 4) = st;
            }
        }
        int w = t * 4 + wv;
#pragma unroll
        for (int u = 0; u < 16; u++) {
            float ss = s[u], qq = q[u];
#pragma unroll
            for (int d = 8; d; d >>= 1) { ss += __shfl_down(ss, d); qq += __shfl_down(qq, d); }
            if (n == 0) {
                int o = (u >> 2) * 16 + quad * 4 + (u & 3);
                p3[(2 * o) * 3200 + w] = ss; p3[(2 * o + 1) * 3200 + w] = qq;
            }
        }
    }
    gridbar(bar, 4);
    // ---- P5: stats3 (blocks 704..767) ----
    if (blk >= 704)
        stats_phase(p3, 3200, g3, be3, prm + 96, prm + 160, (_Float16*)0, (_Float16*)0,
                    blk - 704, 1.f / (1024.f * 100.f), shf);
    gridbar(bar, 5);
    // ---- P6: FC (tanh(BN3) @ fcW^T) -> fpart[oh*100+p][10][1024] ----
    for (int t = blk; t < 800; t += NBLK) {
        int bch = t & 3, q2 = t >> 2;
        int oh = (q2 >= 100) ? 1 : 0, p = q2 - oh * 100;
        int ob = oh * 32;
        __syncthreads();
        for (int idx = tid; idx < 320; idx += 256) {
            int o = idx / 10, jj = idx % 10;
            shf[idx] = fcW[jj * 6400 + (ob + o) * 100 + p];
        }
        if (tid < 32) { shf[320 + tid] = prm[96 + ob + tid]; shf[352 + tid] = prm[160 + ob + tid]; }
        __syncthreads();
        int b = bch * 256 + tid;
        float acc[10];
#pragma unroll
        for (int jj = 0; jj < 10; jj++) acc[jj] = 0.f;
        const _Float16* src = act3h + ((size_t)(p * 1024 + b)) * 64 + ob;
#pragma unroll
        for (int o8 = 0; o8 < 4; o8++) {
            f16x8 xv = *(const f16x8*)(src + o8 * 8);
#pragma unroll
            for (int e = 0; e < 8; e++) {
                int o = o8 * 8 + e;
                float v = fmaf(shf[320 + o], (float)xv[e], shf[352 + o]);
                float e2 = __expf(2.f * v);
                v = 1.f - 2.f / (e2 + 1.f);   // tanh, safe at +/-inf
#pragma unroll
                for (int jj = 0; jj < 10; jj++) acc[jj] = fmaf(shf[o * 10 + jj], v, acc[jj]);
            }
        }
#pragma unroll
        for (int jj = 0; jj < 10; jj++)
            fpart[((size_t)(oh * 100 + p) * 10 + jj) * 1024 + b] = acc[jj];
    }
    gridbar(bar, 6);
    // ---- P7: reduce fc partials + bias -> out (blocks 728..767) ----
    if (blk >= 728) {
        int idx = (blk - 728) * 256 + tid;   // < 10240
        int jj = idx >> 10, b = idx & 1023;
        float acc = fcb[jj];
        for (int g = 0; g < 200; g++) acc += fpart[((size_t)g * 10 + jj) * 1024 + b];
        out[b * 10 + jj] = acc;
    }
}

extern "C" void kernel_launch(void* const* d_in, const int* in_sizes, int n_in,
                              void* d_out, int out_size, void* d_ws, size_t ws_size,
                              hipStream_t stream) {
    const float* x   = (const float*)d_in[0];
    const float* W1  = (const float*)d_in[1];
    const float* b1  = (const float*)d_in[2];
    const float* g1  = (const float*)d_in[3];
    const float* be1 = (const float*)d_in[4];
    const float* W2  = (const float*)d_in[5];
    const float* b2  = (const float*)d_in[6];
    const float* g2  = (const float*)d_in[7];
    const float* be2 = (const float*)d_in[8];
    const float* W3  = (const float*)d_in[9];
    const float* b3  = (const float*)d_in[10];
    const float* g3  = (const float*)d_in[11];
    const float* be3 = (const float*)d_in[12];
    const float* fcW = (const float*)d_in[13];
    const float* fcb = (const float*)d_in[14];
    float* out = (float*)d_out;
    float* ws = (float*)d_ws;

    float* xT       = ws + XT_OFF;
    _Float16* act1h = (_Float16*)(ws + ACT1_OFF);
    _Float16* act2h = (_Float16*)(ws + ACT2_OFF);
    _Float16* act3h = (_Float16*)(ws + ACT3_OFF);
    _Float16* W2h   = (_Float16*)(ws + W2H_OFF);
    _Float16* W3h   = (_Float16*)(ws + W3H_OFF);
    float* p1   = ws + P1_OFF;
    float* p2   = ws + P2_OFF;
    float* p3   = ws + P3_OFF;
    float* fp   = ws + FP_OFF;
    float* prm  = ws + PRM_OFF;
    _Float16* ach = (_Float16*)(ws + ACH_OFF);
    int* bar    = (int*)(ws + BAR_OFF);

    k_prep<<<1269, 256, 0, stream>>>(x, W2, W3, xT, W2h, W3h, bar);
    k_fused<<<NBLK, 256, 0, stream>>>(xT, W1, b1, g1, be1, W2h, b2, g2, be2,
                                      W3h, b3, g3, be3, fcW, fcb,
                                      act1h, act2h, act3h, p1, p2, p3, fp, prm, ach, out, bar);
}

// Round 5
// 405.777 us; speedup vs baseline: 2.2116x; 2.2116x over previous
//
#include <hip/hip_runtime.h>

#define EPS 1e-5f
#define NBLK 768

typedef _Float16 f16x8 __attribute__((ext_vector_type(8)));
typedef _Float16 f16x4 __attribute__((ext_vector_type(4)));
typedef float f32x4 __attribute__((ext_vector_type(4)));

// ---- workspace layout (float offsets) ----
#define XT_OFF    0u          // fp32 256*1024
#define ACT1_OFF  262144u     // f16 196*1024*16
#define ACT2_OFF  1867776u    // f16 144*1024*32
#define ACT3_OFF  4227072u    // f16 100*1024*64
#define W2H_OFF   7503872u    // f16 144*5*32*32
#define W3H_OFF   7872512u    // f16 100*9*64*32
#define P1_OFF    8794112u    // fp32 2*16*3136
#define P2_OFF    8894464u    // fp32 2*32*4608
#define P3_OFF    9189376u    // fp32 2*64*3200
#define FP_OFF    9598976u    // fp32 200*10*1024
#define PRM_OFF   11646976u   // fp32 224
#define ACH_OFF   11647200u   // f16 224 (112 floats)
#define BAR_OFF   11647312u   // int 7*1056 = 7392

// ---------------- prep: weight repack (LDS-staged), x transpose, barrier zero ----------------
__global__ __launch_bounds__(256) void k_prep(const float* __restrict__ x,
                                              const float* __restrict__ W2,
                                              const float* __restrict__ W3,
                                              float* __restrict__ xT,
                                              _Float16* __restrict__ W2h,
                                              _Float16* __restrict__ W3h,
                                              int* __restrict__ bar) {
    __shared__ _Float16 sh[18432];
    __shared__ float tile[16][17];
    int blk = blockIdx.x, tid = threadIdx.x;
    if (blk < 144) {                    // W2 -> W2h [p][t5][o32][k32], pos-pair packed, zero pad
        int p = blk;
        for (int i = tid; i < 5120; i += 256) sh[i] = (_Float16)0.f;
        __syncthreads();
        for (int s = 0; s < 2; s++) {
            int seg = tid + s * 256;    // o*16+c
            int o = seg >> 4, c = seg & 15;
            const float* src = W2 + (size_t)seg * 1296 + p * 9;
#pragma unroll
            for (int pos = 0; pos < 9; pos++) {
                int d = (pos >> 1) * 1024 + o * 32 + (pos & 1) * 16 + c;
                sh[d] = (_Float16)src[pos];
            }
        }
        __syncthreads();
        const int* shi = (const int*)sh;
        int* dst = (int*)(W2h + (size_t)p * 5120);
        for (int i = tid; i < 2560; i += 256) dst[i] = shi[i];
    } else if (blk < 244) {             // W3 -> W3h [p][pos9][o64][c32]
        int p = blk - 144;
        for (int s = 0; s < 8; s++) {
            int seg = tid + s * 256;    // o*32+c
            const float* src = W3 + (size_t)seg * 900 + p * 9;
#pragma unroll
            for (int pos = 0; pos < 9; pos++) sh[pos * 2048 + seg] = (_Float16)src[pos];
        }
        __syncthreads();
        const int* shi = (const int*)sh;
        int* dst = (int*)(W3h + (size_t)p * 18432);
        for (int i = tid; i < 9216; i += 256) dst[i] = shi[i];
    } else if (blk < 1268) {            // x (1024,256) -> xT (256,1024)
        int q = blk - 244;
        int bx = q & 15, by = q >> 4;
        int tx = tid & 15, ty = tid >> 4;
        tile[ty][tx] = x[(by * 16 + ty) * 256 + bx * 16 + tx];
        __syncthreads();
        xT[(bx * 16 + ty) * 1024 + by * 16 + tx] = tile[tx][ty];
    } else {
        for (int i = tid; i < 7392; i += 256) bar[i] = 0;
    }
}

// ---------------- two-level grid barrier: RELAXED atomics + 2 explicit fences ----------------
// R4 lesson: agent-scope ACQUIRE in the poll loop emits buffer_inv (full L2 inv) per poll
// -> 400K invalidates -> ~115us/barrier. Relaxed poll + single acquire fence after exit.
__device__ __forceinline__ void gridbar(int* bar, int k) {
    __syncthreads();
    int* base = bar + k * 1056;
    if (threadIdx.x == 0) {
        __threadfence();   // release: wbl2 once, makes phase writes visible at IF$
        int leaf = blockIdx.x & 63;
        int prev = __hip_atomic_fetch_add(base + leaf * 16, 1, __ATOMIC_RELAXED, __HIP_MEMORY_SCOPE_AGENT);
        if (prev == (NBLK / 64) - 1) {
            int r = __hip_atomic_fetch_add(base + 1024, 1, __ATOMIC_RELAXED, __HIP_MEMORY_SCOPE_AGENT);
            if (r == 63) __hip_atomic_store(base + 1040, 1, __ATOMIC_RELAXED, __HIP_MEMORY_SCOPE_AGENT);
        }
        while (__hip_atomic_load(base + 1040, __ATOMIC_RELAXED, __HIP_MEMORY_SCOPE_AGENT) == 0)
            __builtin_amdgcn_s_sleep(16);
        __threadfence();   // acquire: inv once, so next phase reads fresh data
    }
    __syncthreads();
}

__device__ void stats_phase(const float* __restrict__ part, int nwaves,
                            const float* __restrict__ g, const float* __restrict__ be,
                            float* __restrict__ a, float* __restrict__ c,
                            _Float16* achA, _Float16* achC, int ch, float invN,
                            float* shf) {
    int tid = threadIdx.x;
    const float* ps = part + (size_t)(2 * ch) * nwaves;
    const float* pq = part + (size_t)(2 * ch + 1) * nwaves;
    float s = 0.f, q = 0.f;
    for (int w = tid; w < nwaves; w += 256) { s += ps[w]; q += pq[w]; }
#pragma unroll
    for (int d = 32; d; d >>= 1) { s += __shfl_down(s, d); q += __shfl_down(q, d); }
    if ((tid & 63) == 0) { shf[tid >> 6] = s; shf[4 + (tid >> 6)] = q; }
    __syncthreads();
    if (tid == 0) {
        s = shf[0] + shf[1] + shf[2] + shf[3];
        q = shf[4] + shf[5] + shf[6] + shf[7];
        float m = s * invN;
        float v = q * invN - m * m;
        float r = rsqrtf(v + EPS);
        float av = g[ch] * r, cv = be[ch] - m * av;
        a[ch] = av; c[ch] = cv;
        if (achA) { achA[ch] = (_Float16)av; achC[ch] = (_Float16)cv; }
    }
}

// ---------------- the whole net: 8 phases, 7 grid barriers ----------------
__global__ __launch_bounds__(256, 3) void k_fused(
    const float* __restrict__ xT, const float* __restrict__ W1, const float* __restrict__ b1v,
    const float* __restrict__ g1, const float* __restrict__ be1,
    const _Float16* __restrict__ W2h, const float* __restrict__ b2v,
    const float* __restrict__ g2, const float* __restrict__ be2,
    const _Float16* __restrict__ W3h, const float* __restrict__ b3v,
    const float* __restrict__ g3, const float* __restrict__ be3,
    const float* __restrict__ fcW, const float* __restrict__ fcb,
    _Float16* __restrict__ act1h, _Float16* __restrict__ act2h, _Float16* __restrict__ act3h,
    float* __restrict__ p1, float* __restrict__ p2, float* __restrict__ p3,
    float* __restrict__ fpart, float* __restrict__ prm, _Float16* __restrict__ ach,
    float* __restrict__ out, int* __restrict__ bar) {
    __shared__ float shf[448];
    int blk = blockIdx.x, tid = threadIdx.x;
    int wv = tid >> 6, lane = tid & 63;
    int n = lane & 15, quad = lane >> 4;

    // ---- P0: LC1 (fp32 VALU) ----
    for (int t = blk; t < 784; t += NBLK) {
        int p = t % 196, bch = t / 196;
        int i = p / 14, j = p % 14;
        __syncthreads();
        if (tid < 144) { int o = tid / 9, k = tid % 9; shf[tid] = W1[(o * 196 + p) * 9 + k]; }
        if (tid < 16) shf[144 + tid] = b1v[tid * 196 + p];
        __syncthreads();
        int b = bch * 256 + tid;
        float xv[9];
#pragma unroll
        for (int di = 0; di < 3; di++)
#pragma unroll
            for (int dj = 0; dj < 3; dj++)
                xv[di * 3 + dj] = xT[((i + di) * 16 + (j + dj)) * 1024 + b];
        float accv[16];
#pragma unroll
        for (int o = 0; o < 16; o++) {
            float acc = shf[144 + o];
#pragma unroll
            for (int k = 0; k < 9; k++) acc += shf[o * 9 + k] * xv[k];
            accv[o] = acc;
        }
        f16x8 lo, hi;
#pragma unroll
        for (int e = 0; e < 8; e++) { lo[e] = (_Float16)accv[e]; hi[e] = (_Float16)accv[8 + e]; }
        _Float16* dst = act1h + ((size_t)(p * 1024 + b)) * 16;
        *(f16x8*)dst = lo;
        *(f16x8*)(dst + 8) = hi;
        int w = (bch * 196 + p) * 4 + wv;
#pragma unroll
        for (int o = 0; o < 16; o++) {
            float s = accv[o], q = accv[o] * accv[o];
#pragma unroll
            for (int d = 32; d; d >>= 1) { s += __shfl_down(s, d); q += __shfl_down(q, d); }
            if (lane == 0) { p1[(2 * o) * 3136 + w] = s; p1[(2 * o + 1) * 3136 + w] = q; }
        }
    }
    gridbar(bar, 0);
    // ---- P1: stats1 (blocks 752..767) ----
    if (blk >= 752)
        stats_phase(p1, 3136, g1, be1, prm, prm + 16, ach, ach + 16, blk - 752,
                    1.f / (1024.f * 196.f), shf);
    gridbar(bar, 1);
    // ---- P2: LC2 MFMA ----
    for (int t = blk; t < 1152; t += NBLK) {
        int p = t >> 3, bg = t & 7;
        int i = p / 12, j = p % 12;
        int bbase = bg * 128 + wv * 32;
        f16x8 a8 = *(const f16x8*)(ach + (quad & 1) * 8);
        f16x8 c8 = *(const f16x8*)(ach + 16 + (quad & 1) * 8);
        f32x4 acc[2][2] = {};
#pragma unroll
        for (int tt = 0; tt < 5; tt++) {
            int pos0 = 2 * tt, pos1 = (2 * tt + 1 < 9) ? 2 * tt + 1 : 8;
            int mypos = (quad >> 1) ? pos1 : pos0;
            int ip = (i + mypos / 3) * 14 + (j + mypos % 3);
            f16x8 bfr[2];
#pragma unroll
            for (int nt = 0; nt < 2; nt++) {
                f16x8 x = *(const f16x8*)(act1h + ((size_t)(ip * 1024 + bbase + nt * 16 + n)) * 16 + (quad & 1) * 8);
#pragma unroll
                for (int e = 0; e < 8; e++) {
                    _Float16 v = x[e] * a8[e] + c8[e];
                    x[e] = v > (_Float16)0.f ? v : (_Float16)0.f;
                }
                bfr[nt] = x;
            }
            f16x8 afr[2];
#pragma unroll
            for (int ot = 0; ot < 2; ot++)
                afr[ot] = *(const f16x8*)(W2h + ((size_t)((p * 5 + tt) * 32 + ot * 16 + n)) * 32 + quad * 8);
#pragma unroll
            for (int ot = 0; ot < 2; ot++)
#pragma unroll
                for (int nt = 0; nt < 2; nt++)
                    acc[ot][nt] = __builtin_amdgcn_mfma_f32_16x16x32_f16(afr[ot], bfr[nt], acc[ot][nt], 0, 0, 0);
        }
        float s[8] = {}, q[8] = {};
#pragma unroll
        for (int ot = 0; ot < 2; ot++) {
            float bias[4];
#pragma unroll
            for (int r = 0; r < 4; r++) bias[r] = b2v[(ot * 16 + quad * 4 + r) * 144 + p];
#pragma unroll
            for (int nt = 0; nt < 2; nt++) {
                int b = bbase + nt * 16 + n;
                f16x4 st;
#pragma unroll
                for (int r = 0; r < 4; r++) {
                    float v = acc[ot][nt][r] + bias[r];
                    st[r] = (_Float16)v;
                    s[ot * 4 + r] += v; q[ot * 4 + r] += v * v;
                }
                *(f16x4*)(act2h + ((size_t)(p * 1024 + b)) * 32 + ot * 16 + quad * 4) = st;
            }
        }
        int w = t * 4 + wv;
#pragma unroll
        for (int u = 0; u < 8; u++) {
            float ss = s[u], qq = q[u];
#pragma unroll
            for (int d = 8; d; d >>= 1) { ss += __shfl_down(ss, d); qq += __shfl_down(qq, d); }
            if (n == 0) {
                int o = (u >> 2) * 16 + quad * 4 + (u & 3);
                p2[(2 * o) * 4608 + w] = ss; p2[(2 * o + 1) * 4608 + w] = qq;
            }
        }
    }
    gridbar(bar, 2);
    // ---- P3: stats2 (blocks 736..767) ----
    if (blk >= 736)
        stats_phase(p2, 4608, g2, be2, prm + 32, prm + 64, ach + 32, ach + 64, blk - 736,
                    1.f / (1024.f * 144.f), shf);
    gridbar(bar, 3);
    // ---- P4: LC3 MFMA ----
    for (int t = blk; t < 800; t += NBLK) {
        int p = t >> 3, bg = t & 7;
        int i = p / 10, j = p % 10;
        int bbase = bg * 128 + wv * 32;
        f16x8 a8 = *(const f16x8*)(ach + 32 + quad * 8);
        f16x8 c8 = *(const f16x8*)(ach + 64 + quad * 8);
        f32x4 acc[4][2] = {};
#pragma unroll
        for (int pos = 0; pos < 9; pos++) {
            int ip = (i + pos / 3) * 12 + (j + pos % 3);
            f16x8 bfr[2];
#pragma unroll
            for (int nt = 0; nt < 2; nt++) {
                f16x8 x = *(const f16x8*)(act2h + ((size_t)(ip * 1024 + bbase + nt * 16 + n)) * 32 + quad * 8);
#pragma unroll
                for (int e = 0; e < 8; e++) {
                    _Float16 v = x[e] * a8[e] + c8[e];
                    x[e] = v > (_Float16)0.f ? v : (_Float16)0.f;
                }
                bfr[nt] = x;
            }
            f16x8 afr[4];
#pragma unroll
            for (int ot = 0; ot < 4; ot++)
                afr[ot] = *(const f16x8*)(W3h + ((size_t)((p * 9 + pos) * 64 + ot * 16 + n)) * 32 + quad * 8);
#pragma unroll
            for (int ot = 0; ot < 4; ot++)
#pragma unroll
                for (int nt = 0; nt < 2; nt++)
                    acc[ot][nt] = __builtin_amdgcn_mfma_f32_16x16x32_f16(afr[ot], bfr[nt], acc[ot][nt], 0, 0, 0);
        }
        float s[16] = {}, q[16] = {};
#pragma unroll
        for (int ot = 0; ot < 4; ot++) {
            float bias[4];
#pragma unroll
            for (int r = 0; r < 4; r++) bias[r] = b3v[(ot * 16 + quad * 4 + r) * 100 + p];
#pragma unroll
            for (int nt = 0; nt < 2; nt++) {
                int b = bbase + nt * 16 + n;
                f16x4 st;
#pragma unroll
                for (int r = 0; r < 4; r++) {
                    float v = acc[ot][nt][r] + bias[r];
                    st[r] = (_Float16)v;
                    s[ot * 4 + r] += v; q[ot * 4 + r] += v * v;
                }
                *(f16x4*)(act3h + ((size_t)(p * 1024 + b)) * 64 + ot * 16 + quad * 4) = st;
            }
        }
        int w = t * 4 + wv;
#pragma unroll
        for (int u = 0; u < 16; u++) {
            float ss = s[u], qq = q[u];
#pragma unroll
            for (int d = 8; d; d >>= 1) { ss += __shfl_down(ss, d); qq += __shfl_down(qq, d); }
            if (n == 0) {
                int o = (u >> 2) * 16 + quad * 4 + (u & 3);
                p3[(2 * o) * 3200 + w] = ss; p3[(2 * o + 1) * 3200 + w] = qq;
            }
        }
    }
    gridbar(bar, 4);
    // ---- P5: stats3 (blocks 704..767) ----
    if (blk >= 704)
        stats_phase(p3, 3200, g3, be3, prm + 96, prm + 160, (_Float16*)0, (_Float16*)0,
                    blk - 704, 1.f / (1024.f * 100.f), shf);
    gridbar(bar, 5);
    // ---- P6: FC (tanh(BN3) @ fcW^T) -> fpart[oh*100+p][10][1024] ----
    for (int t = blk; t < 800; t += NBLK) {
        int bch = t & 3, q2 = t >> 2;
        int oh = (q2 >= 100) ? 1 : 0, p = q2 - oh * 100;
        int ob = oh * 32;
        __syncthreads();
        for (int idx = tid; idx < 320; idx += 256) {
            int o = idx / 10, jj = idx % 10;
            shf[idx] = fcW[jj * 6400 + (ob + o) * 100 + p];
        }
        if (tid < 32) { shf[320 + tid] = prm[96 + ob + tid]; shf[352 + tid] = prm[160 + ob + tid]; }
        __syncthreads();
        int b = bch * 256 + tid;
        float acc[10];
#pragma unroll
        for (int jj = 0; jj < 10; jj++) acc[jj] = 0.f;
        const _Float16* src = act3h + ((size_t)(p * 1024 + b)) * 64 + ob;
#pragma unroll
        for (int o8 = 0; o8 < 4; o8++) {
            f16x8 xv = *(const f16x8*)(src + o8 * 8);
#pragma unroll
            for (int e = 0; e < 8; e++) {
                int o = o8 * 8 + e;
                float v = fmaf(shf[320 + o], (float)xv[e], shf[352 + o]);
                float e2 = __expf(2.f * v);
                v = 1.f - 2.f / (e2 + 1.f);   // tanh, safe at +/-inf
#pragma unroll
                for (int jj = 0; jj < 10; jj++) acc[jj] = fmaf(shf[o * 10 + jj], v, acc[jj]);
            }
        }
#pragma unroll
        for (int jj = 0; jj < 10; jj++)
            fpart[((size_t)(oh * 100 + p) * 10 + jj) * 1024 + b] = acc[jj];
    }
    gridbar(bar, 6);
    // ---- P7: reduce fc partials + bias -> out (blocks 728..767) ----
    if (blk >= 728) {
        int idx = (blk - 728) * 256 + tid;   // < 10240
        int jj = idx >> 10, b = idx & 1023;
        float acc = fcb[jj];
        for (int g = 0; g < 200; g++) acc += fpart[((size_t)g * 10 + jj) * 1024 + b];
        out[b * 10 + jj] = acc;
    }
}

extern "C" void kernel_launch(void* const* d_in, const int* in_sizes, int n_in,
                              void* d_out, int out_size, void* d_ws, size_t ws_size,
                              hipStream_t stream) {
    const float* x   = (const float*)d_in[0];
    const float* W1  = (const float*)d_in[1];
    const float* b1  = (const float*)d_in[2];
    const float* g1  = (const float*)d_in[3];
    const float* be1 = (const float*)d_in[4];
    const float* W2  = (const float*)d_in[5];
    const float* b2  = (const float*)d_in[6];
    const float* g2  = (const float*)d_in[7];
    const float* be2 = (const float*)d_in[8];
    const float* W3  = (const float*)d_in[9];
    const float* b3  = (const float*)d_in[10];
    const float* g3  = (const float*)d_in[11];
    const float* be3 = (const float*)d_in[12];
    const float* fcW = (const float*)d_in[13];
    const float* fcb = (const float*)d_in[14];
    float* out = (float*)d_out;
    float* ws = (float*)d_ws;

    float* xT       = ws + XT_OFF;
    _Float16* act1h = (_Float16*)(ws + ACT1_OFF);
    _Float16* act2h = (_Float16*)(ws + ACT2_OFF);
    _Float16* act3h = (_Float16*)(ws + ACT3_OFF);
    _Float16* W2h   = (_Float16*)(ws + W2H_OFF);
    _Float16* W3h   = (_Float16*)(ws + W3H_OFF);
    float* p1   = ws + P1_OFF;
    float* p2   = ws + P2_OFF;
    float* p3   = ws + P3_OFF;
    float* fp   = ws + FP_OFF;
    float* prm  = ws + PRM_OFF;
    _Float16* ach = (_Float16*)(ws + ACH_OFF);
    int* bar    = (int*)(ws + BAR_OFF);

    k_prep<<<1269, 256, 0, stream>>>(x, W2, W3, xT, W2h, W3h, bar);
    k_fused<<<NBLK, 256, 0, stream>>>(xT, W1, b1, g1, be1, W2h, b2, g2, be2,
                                      W3h, b3, g3, be3, fcW, fcb,
                                      act1h, act2h, act3h, p1, p2, p3, fp, prm, ach, out, bar);
}

// Round 6
// 213.312 us; speedup vs baseline: 4.2071x; 1.9023x over previous
//
#include <hip/hip_runtime.h>

#define EPS 1e-5f
#define NBLK 768

typedef _Float16 f16x8 __attribute__((ext_vector_type(8)));
typedef _Float16 f16x4 __attribute__((ext_vector_type(4)));
typedef float f32x4 __attribute__((ext_vector_type(4)));

// ---- workspace layout (float offsets) ----
#define XT_OFF    0u          // fp32 256*1024
#define ACT1_OFF  262144u     // f16 196*1024*16
#define ACT2_OFF  1867776u    // f16 144*1024*32
#define ACT3_OFF  4227072u    // f16 100*1024*64
#define W2H_OFF   7503872u    // f16 144*5*32*32
#define W3H_OFF   7872512u    // f16 100*9*64*32
#define P1_OFF    8794112u    // fp32 2*16*3136
#define P2_OFF    8894464u    // fp32 2*32*4608
#define P3_OFF    9189376u    // fp32 2*64*3200
#define FP_OFF    9598976u    // fp32 200*10*1024
#define PRM_OFF   11646976u   // fp32 224
#define ACH_OFF   11647200u   // f16 224 (112 floats)
#define BAR_OFF   11647312u   // int region, 7392 zeroed
// bar int layout: [0..127] xcd reg counters (8 x 16-stride); [128] reg_done;
// per-barrier k: base=160+k*320: [x*16] arrive, [128] root, [144] flag, [160+x*16] xflag

#define AGENT __HIP_MEMORY_SCOPE_AGENT
#define RLX __ATOMIC_RELAXED

// ---------------- prep: weight repack (LDS-staged), x transpose, barrier zero ----------------
__global__ __launch_bounds__(256) void k_prep(const float* __restrict__ x,
                                              const float* __restrict__ W2,
                                              const float* __restrict__ W3,
                                              float* __restrict__ xT,
                                              _Float16* __restrict__ W2h,
                                              _Float16* __restrict__ W3h,
                                              int* __restrict__ bar) {
    __shared__ _Float16 sh[18432];
    __shared__ float tile[16][17];
    int blk = blockIdx.x, tid = threadIdx.x;
    if (blk < 144) {                    // W2 -> W2h [p][t5][o32][k32], pos-pair packed, zero pad
        int p = blk;
        for (int i = tid; i < 5120; i += 256) sh[i] = (_Float16)0.f;
        __syncthreads();
        for (int s = 0; s < 2; s++) {
            int seg = tid + s * 256;    // o*16+c
            int o = seg >> 4, c = seg & 15;
            const float* src = W2 + (size_t)seg * 1296 + p * 9;
#pragma unroll
            for (int pos = 0; pos < 9; pos++) {
                int d = (pos >> 1) * 1024 + o * 32 + (pos & 1) * 16 + c;
                sh[d] = (_Float16)src[pos];
            }
        }
        __syncthreads();
        const int* shi = (const int*)sh;
        int* dst = (int*)(W2h + (size_t)p * 5120);
        for (int i = tid; i < 2560; i += 256) dst[i] = shi[i];
    } else if (blk < 244) {             // W3 -> W3h [p][pos9][o64][c32]
        int p = blk - 144;
        for (int s = 0; s < 8; s++) {
            int seg = tid + s * 256;    // o*32+c
            const float* src = W3 + (size_t)seg * 900 + p * 9;
#pragma unroll
            for (int pos = 0; pos < 9; pos++) sh[pos * 2048 + seg] = (_Float16)src[pos];
        }
        __syncthreads();
        const int* shi = (const int*)sh;
        int* dst = (int*)(W3h + (size_t)p * 18432);
        for (int i = tid; i < 9216; i += 256) dst[i] = shi[i];
    } else if (blk < 1268) {            // x (1024,256) -> xT (256,1024)
        int q = blk - 244;
        int bx = q & 15, by = q >> 4;
        int tx = tid & 15, ty = tid >> 4;
        tile[ty][tx] = x[(by * 16 + ty) * 256 + bx * 16 + tx];
        __syncthreads();
        xT[(bx * 16 + ty) * 1024 + by * 16 + tx] = tile[tx][ty];
    } else {
        for (int i = tid; i < 7392; i += 256) bar[i] = 0;
    }
}

// ---------------- XCD-grouped grid barrier ----------------
// R5 lesson: 1536 threadfences (full-L2 wbl2+inv each) + 768 pollers on one MALL line
// per barrier. Fix: exactly 8 wbl2 (last arriver per physical XCD) + 8 inv (leader per
// XCD), hierarchical release (8 leaders poll root; ~95 followers poll per-XCD line).
__device__ __forceinline__ void gridbar(int* bar, int k, int myxcd, int xcnt, int nact) {
    __syncthreads();   // all waves' stores at vmcnt0 -> resident in this XCD's L2
    if (threadIdx.x == 0) {
        int* base = bar + 160 + k * 320;
        int prev = __hip_atomic_fetch_add(base + myxcd * 16, 1, RLX, AGENT);
        if (prev == xcnt - 1) {          // last block on this XCD: flush its L2 once
            asm volatile("buffer_wbl2\n\ts_waitcnt vmcnt(0)" ::: "memory");
            int r = __hip_atomic_fetch_add(base + 128, 1, RLX, AGENT);
            if (r == nact - 1)
                __hip_atomic_store(base + 144, 1, RLX, AGENT);
        }
        if (prev == 0) {                 // first arriver = XCD leader
            int guard = 0;
            while (__hip_atomic_load(base + 144, RLX, AGENT) == 0 && ++guard < (1 << 18))
                __builtin_amdgcn_s_sleep(16);
            asm volatile("buffer_inv\n\ts_waitcnt vmcnt(0)" ::: "memory");
            __hip_atomic_store(base + 160 + myxcd * 16, 1, RLX, AGENT);
        } else {
            int guard = 0;
            while (__hip_atomic_load(base + 160 + myxcd * 16, RLX, AGENT) == 0 && ++guard < (1 << 18))
                __builtin_amdgcn_s_sleep(16);
        }
    }
    __syncthreads();
}

__device__ void stats_phase(const float* __restrict__ part, int nwaves,
                            const float* __restrict__ g, const float* __restrict__ be,
                            float* __restrict__ a, float* __restrict__ c,
                            _Float16* achA, _Float16* achC, int ch, float invN,
                            float* shf) {
    int tid = threadIdx.x;
    const float* ps = part + (size_t)(2 * ch) * nwaves;
    const float* pq = part + (size_t)(2 * ch + 1) * nwaves;
    float s = 0.f, q = 0.f;
    for (int w = tid; w < nwaves; w += 256) { s += ps[w]; q += pq[w]; }
#pragma unroll
    for (int d = 32; d; d >>= 1) { s += __shfl_down(s, d); q += __shfl_down(q, d); }
    if ((tid & 63) == 0) { shf[tid >> 6] = s; shf[4 + (tid >> 6)] = q; }
    __syncthreads();
    if (tid == 0) {
        s = shf[0] + shf[1] + shf[2] + shf[3];
        q = shf[4] + shf[5] + shf[6] + shf[7];
        float m = s * invN;
        float v = q * invN - m * m;
        float r = rsqrtf(v + EPS);
        float av = g[ch] * r, cv = be[ch] - m * av;
        a[ch] = av; c[ch] = cv;
        if (achA) { achA[ch] = (_Float16)av; achC[ch] = (_Float16)cv; }
    }
}

// ---------------- the whole net: 8 phases, 7 grid barriers ----------------
__global__ __launch_bounds__(256, 3) void k_fused(
    const float* __restrict__ xT, const float* __restrict__ W1, const float* __restrict__ b1v,
    const float* __restrict__ g1, const float* __restrict__ be1,
    const _Float16* __restrict__ W2h, const float* __restrict__ b2v,
    const float* __restrict__ g2, const float* __restrict__ be2,
    const _Float16* __restrict__ W3h, const float* __restrict__ b3v,
    const float* __restrict__ g3, const float* __restrict__ be3,
    const float* __restrict__ fcW, const float* __restrict__ fcb,
    _Float16* __restrict__ act1h, _Float16* __restrict__ act2h, _Float16* __restrict__ act3h,
    float* __restrict__ p1, float* __restrict__ p2, float* __restrict__ p3,
    float* __restrict__ fpart, float* __restrict__ prm, _Float16* __restrict__ ach,
    float* __restrict__ out, int* __restrict__ bar) {
    __shared__ float shf[448];
    int blk = blockIdx.x, tid = threadIdx.x;
    int wv = tid >> 6, lane = tid & 63;
    int n = lane & 15, quad = lane >> 4;

    // ---- registration: count blocks per physical XCD ----
    int myxcd = 0, xcnt = 0, nact = 0;
    if (tid == 0) {
        asm volatile("s_getreg_b32 %0, hwreg(HW_REG_XCC_ID, 0, 4)" : "=s"(myxcd));
        myxcd &= 7;
        __hip_atomic_fetch_add(bar + myxcd * 16, 1, RLX, AGENT);
        asm volatile("s_waitcnt vmcnt(0)" ::: "memory");   // cnt add completes before done add
        __hip_atomic_fetch_add(bar + 128, 1, RLX, AGENT);
    }

    // ---- P0: LC1 (fp32 VALU) ----
    for (int t = blk; t < 784; t += NBLK) {
        int p = t % 196, bch = t / 196;
        int i = p / 14, j = p % 14;
        __syncthreads();
        if (tid < 144) { int o = tid / 9, k = tid % 9; shf[tid] = W1[(o * 196 + p) * 9 + k]; }
        if (tid < 16) shf[144 + tid] = b1v[tid * 196 + p];
        __syncthreads();
        int b = bch * 256 + tid;
        float xv[9];
#pragma unroll
        for (int di = 0; di < 3; di++)
#pragma unroll
            for (int dj = 0; dj < 3; dj++)
                xv[di * 3 + dj] = xT[((i + di) * 16 + (j + dj)) * 1024 + b];
        float accv[16];
#pragma unroll
        for (int o = 0; o < 16; o++) {
            float acc = shf[144 + o];
#pragma unroll
            for (int k = 0; k < 9; k++) acc += shf[o * 9 + k] * xv[k];
            accv[o] = acc;
        }
        f16x8 lo, hi;
#pragma unroll
        for (int e = 0; e < 8; e++) { lo[e] = (_Float16)accv[e]; hi[e] = (_Float16)accv[8 + e]; }
        _Float16* dst = act1h + ((size_t)(p * 1024 + b)) * 16;
        *(f16x8*)dst = lo;
        *(f16x8*)(dst + 8) = hi;
        int w = (bch * 196 + p) * 4 + wv;
#pragma unroll
        for (int o = 0; o < 16; o++) {
            float s = accv[o], q = accv[o] * accv[o];
#pragma unroll
            for (int d = 32; d; d >>= 1) { s += __shfl_down(s, d); q += __shfl_down(q, d); }
            if (lane == 0) { p1[(2 * o) * 3136 + w] = s; p1[(2 * o + 1) * 3136 + w] = q; }
        }
    }
    // ---- resolve registration (P0 work above gave it ample time) ----
    if (tid == 0) {
        int guard = 0;
        while (__hip_atomic_load(bar + 128, RLX, AGENT) != NBLK && ++guard < (1 << 18))
            __builtin_amdgcn_s_sleep(16);
        for (int x2 = 0; x2 < 8; x2++) {
            int v = __hip_atomic_load(bar + x2 * 16, RLX, AGENT);
            if (x2 == myxcd) xcnt = v;
            nact += (v != 0);
        }
    }
    gridbar(bar, 0, myxcd, xcnt, nact);
    // ---- P1: stats1 (blocks 752..767) ----
    if (blk >= 752)
        stats_phase(p1, 3136, g1, be1, prm, prm + 16, ach, ach + 16, blk - 752,
                    1.f / (1024.f * 196.f), shf);
    gridbar(bar, 1, myxcd, xcnt, nact);
    // ---- P2: LC2 MFMA ----
    for (int t = blk; t < 1152; t += NBLK) {
        int p = t >> 3, bg = t & 7;
        int i = p / 12, j = p % 12;
        int bbase = bg * 128 + wv * 32;
        f16x8 a8 = *(const f16x8*)(ach + (quad & 1) * 8);
        f16x8 c8 = *(const f16x8*)(ach + 16 + (quad & 1) * 8);
        f32x4 acc[2][2] = {};
#pragma unroll
        for (int tt = 0; tt < 5; tt++) {
            int pos0 = 2 * tt, pos1 = (2 * tt + 1 < 9) ? 2 * tt + 1 : 8;
            int mypos = (quad >> 1) ? pos1 : pos0;
            int ip = (i + mypos / 3) * 14 + (j + mypos % 3);
            f16x8 bfr[2];
#pragma unroll
            for (int nt = 0; nt < 2; nt++) {
                f16x8 x = *(const f16x8*)(act1h + ((size_t)(ip * 1024 + bbase + nt * 16 + n)) * 16 + (quad & 1) * 8);
#pragma unroll
                for (int e = 0; e < 8; e++) {
                    _Float16 v = x[e] * a8[e] + c8[e];
                    x[e] = v > (_Float16)0.f ? v : (_Float16)0.f;
                }
                bfr[nt] = x;
            }
            f16x8 afr[2];
#pragma unroll
            for (int ot = 0; ot < 2; ot++)
                afr[ot] = *(const f16x8*)(W2h + ((size_t)((p * 5 + tt) * 32 + ot * 16 + n)) * 32 + quad * 8);
#pragma unroll
            for (int ot = 0; ot < 2; ot++)
#pragma unroll
                for (int nt = 0; nt < 2; nt++)
                    acc[ot][nt] = __builtin_amdgcn_mfma_f32_16x16x32_f16(afr[ot], bfr[nt], acc[ot][nt], 0, 0, 0);
        }
        float s[8] = {}, q[8] = {};
#pragma unroll
        for (int ot = 0; ot < 2; ot++) {
            float bias[4];
#pragma unroll
            for (int r = 0; r < 4; r++) bias[r] = b2v[(ot * 16 + quad * 4 + r) * 144 + p];
#pragma unroll
            for (int nt = 0; nt < 2; nt++) {
                int b = bbase + nt * 16 + n;
                f16x4 st;
#pragma unroll
                for (int r = 0; r < 4; r++) {
                    float v = acc[ot][nt][r] + bias[r];
                    st[r] = (_Float16)v;
                    s[ot * 4 + r] += v; q[ot * 4 + r] += v * v;
                }
                *(f16x4*)(act2h + ((size_t)(p * 1024 + b)) * 32 + ot * 16 + quad * 4) = st;
            }
        }
        int w = t * 4 + wv;
#pragma unroll
        for (int u = 0; u < 8; u++) {
            float ss = s[u], qq = q[u];
#pragma unroll
            for (int d = 8; d; d >>= 1) { ss += __shfl_down(ss, d); qq += __shfl_down(qq, d); }
            if (n == 0) {
                int o = (u >> 2) * 16 + quad * 4 + (u & 3);
                p2[(2 * o) * 4608 + w] = ss; p2[(2 * o + 1) * 4608 + w] = qq;
            }
        }
    }
    gridbar(bar, 2, myxcd, xcnt, nact);
    // ---- P3: stats2 (blocks 736..767) ----
    if (blk >= 736)
        stats_phase(p2, 4608, g2, be2, prm + 32, prm + 64, ach + 32, ach + 64, blk - 736,
                    1.f / (1024.f * 144.f), shf);
    gridbar(bar, 3, myxcd, xcnt, nact);
    // ---- P4: LC3 MFMA ----
    for (int t = blk; t < 800; t += NBLK) {
        int p = t >> 3, bg = t & 7;
        int i = p / 10, j = p % 10;
        int bbase = bg * 128 + wv * 32;
        f16x8 a8 = *(const f16x8*)(ach + 32 + quad * 8);
        f16x8 c8 = *(const f16x8*)(ach + 64 + quad * 8);
        f32x4 acc[4][2] = {};
#pragma unroll
        for (int pos = 0; pos < 9; pos++) {
            int ip = (i + pos / 3) * 12 + (j + pos % 3);
            f16x8 bfr[2];
#pragma unroll
            for (int nt = 0; nt < 2; nt++) {
                f16x8 x = *(const f16x8*)(act2h + ((size_t)(ip * 1024 + bbase + nt * 16 + n)) * 32 + quad * 8);
#pragma unroll
                for (int e = 0; e < 8; e++) {
                    _Float16 v = x[e] * a8[e] + c8[e];
                    x[e] = v > (_Float16)0.f ? v : (_Float16)0.f;
                }
                bfr[nt] = x;
            }
            f16x8 afr[4];
#pragma unroll
            for (int ot = 0; ot < 4; ot++)
                afr[ot] = *(const f16x8*)(W3h + ((size_t)((p * 9 + pos) * 64 + ot * 16 + n)) * 32 + quad * 8);
#pragma unroll
            for (int ot = 0; ot < 4; ot++)
#pragma unroll
                for (int nt = 0; nt < 2; nt++)
                    acc[ot][nt] = __builtin_amdgcn_mfma_f32_16x16x32_f16(afr[ot], bfr[nt], acc[ot][nt], 0, 0, 0);
        }
        float s[16] = {}, q[16] = {};
#pragma unroll
        for (int ot = 0; ot < 4; ot++) {
            float bias[4];
#pragma unroll
            for (int r = 0; r < 4; r++) bias[r] = b3v[(ot * 16 + quad * 4 + r) * 100 + p];
#pragma unroll
            for (int nt = 0; nt < 2; nt++) {
                int b = bbase + nt * 16 + n;
                f16x4 st;
#pragma unroll
                for (int r = 0; r < 4; r++) {
                    float v = acc[ot][nt][r] + bias[r];
                    st[r] = (_Float16)v;
                    s[ot * 4 + r] += v; q[ot * 4 + r] += v * v;
                }
                *(f16x4*)(act3h + ((size_t)(p * 1024 + b)) * 64 + ot * 16 + quad * 4) = st;
            }
        }
        int w = t * 4 + wv;
#pragma unroll
        for (int u = 0; u < 16; u++) {
            float ss = s[u], qq = q[u];
#pragma unroll
            for (int d = 8; d; d >>= 1) { ss += __shfl_down(ss, d); qq += __shfl_down(qq, d); }
            if (n == 0) {
                int o = (u >> 2) * 16 + quad * 4 + (u & 3);
                p3[(2 * o) * 3200 + w] = ss; p3[(2 * o + 1) * 3200 + w] = qq;
            }
        }
    }
    gridbar(bar, 4, myxcd, xcnt, nact);
    // ---- P5: stats3 (blocks 704..767) ----
    if (blk >= 704)
        stats_phase(p3, 3200, g3, be3, prm + 96, prm + 160, (_Float16*)0, (_Float16*)0,
                    blk - 704, 1.f / (1024.f * 100.f), shf);
    gridbar(bar, 5, myxcd, xcnt, nact);
    // ---- P6: FC (tanh(BN3) @ fcW^T) -> fpart[oh*100+p][10][1024] ----
    for (int t = blk; t < 800; t += NBLK) {
        int bch = t & 3, q2 = t >> 2;
        int oh = (q2 >= 100) ? 1 : 0, p = q2 - oh * 100;
        int ob = oh * 32;
        __syncthreads();
        for (int idx = tid; idx < 320; idx += 256) {
            int o = idx / 10, jj = idx % 10;
            shf[idx] = fcW[jj * 6400 + (ob + o) * 100 + p];
        }
        if (tid < 32) { shf[320 + tid] = prm[96 + ob + tid]; shf[352 + tid] = prm[160 + ob + tid]; }
        __syncthreads();
        int b = bch * 256 + tid;
        float acc[10];
#pragma unroll
        for (int jj = 0; jj < 10; jj++) acc[jj] = 0.f;
        const _Float16* src = act3h + ((size_t)(p * 1024 + b)) * 64 + ob;
#pragma unroll
        for (int o8 = 0; o8 < 4; o8++) {
            f16x8 xv = *(const f16x8*)(src + o8 * 8);
#pragma unroll
            for (int e = 0; e < 8; e++) {
                int o = o8 * 8 + e;
                float v = fmaf(shf[320 + o], (float)xv[e], shf[352 + o]);
                float e2 = __expf(2.f * v);
                v = 1.f - 2.f / (e2 + 1.f);   // tanh, safe at +/-inf
#pragma unroll
                for (int jj = 0; jj < 10; jj++) acc[jj] = fmaf(shf[o * 10 + jj], v, acc[jj]);
            }
        }
#pragma unroll
        for (int jj = 0; jj < 10; jj++)
            fpart[((size_t)(oh * 100 + p) * 10 + jj) * 1024 + b] = acc[jj];
    }
    gridbar(bar, 6, myxcd, xcnt, nact);
    // ---- P7: reduce fc partials + bias -> out (blocks 728..767) ----
    if (blk >= 728) {
        int idx = (blk - 728) * 256 + tid;   // < 10240
        int jj = idx >> 10, b = idx & 1023;
        float acc = fcb[jj];
        for (int g = 0; g < 200; g++) acc += fpart[((size_t)g * 10 + jj) * 1024 + b];
        out[b * 10 + jj] = acc;
    }
}

extern "C" void kernel_launch(void* const* d_in, const int* in_sizes, int n_in,
                              void* d_out, int out_size, void* d_ws, size_t ws_size,
                              hipStream_t stream) {
    const float* x   = (const float*)d_in[0];
    const float* W1  = (const float*)d_in[1];
    const float* b1  = (const float*)d_in[2];
    const float* g1  = (const float*)d_in[3];
    const float* be1 = (const float*)d_in[4];
    const float* W2  = (const float*)d_in[5];
    const float* b2  = (const float*)d_in[6];
    const float* g2  = (const float*)d_in[7];
    const float* be2 = (const float*)d_in[8];
    const float* W3  = (const float*)d_in[9];
    const float* b3  = (const float*)d_in[10];
    const float* g3  = (const float*)d_in[11];
    const float* be3 = (const float*)d_in[12];
    const float* fcW = (const float*)d_in[13];
    const float* fcb = (const float*)d_in[14];
    float* out = (float*)d_out;
    float* ws = (float*)d_ws;

    float* xT       = ws + XT_OFF;
    _Float16* act1h = (_Float16*)(ws + ACT1_OFF);
    _Float16* act2h = (_Float16*)(ws + ACT2_OFF);
    _Float16* act3h = (_Float16*)(ws + ACT3_OFF);
    _Float16* W2h   = (_Float16*)(ws + W2H_OFF);
    _Float16* W3h   = (_Float16*)(ws + W3H_OFF);
    float* p1   = ws + P1_OFF;
    float* p2   = ws + P2_OFF;
    float* p3   = ws + P3_OFF;
    float* fp   = ws + FP_OFF;
    float* prm  = ws + PRM_OFF;
    _Float16* ach = (_Float16*)(ws + ACH_OFF);
    int* bar    = (int*)(ws + BAR_OFF);

    k_prep<<<1269, 256, 0, stream>>>(x, W2, W3, xT, W2h, W3h, bar);
    k_fused<<<NBLK, 256, 0, stream>>>(xT, W1, b1, g1, be1, W2h, b2, g2, be2,
                                      W3h, b3, g3, be3, fcW, fcb,
                                      act1h, act2h, act3h, p1, p2, p3, fp, prm, ach, out, bar);
}

// Round 7
// 210.534 us; speedup vs baseline: 4.2626x; 1.0132x over previous
//
#include <hip/hip_runtime.h>

#define EPS 1e-5f
#define NBLK 768

typedef _Float16 f16x8 __attribute__((ext_vector_type(8)));
typedef _Float16 f16x4 __attribute__((ext_vector_type(4)));
typedef float f32x4 __attribute__((ext_vector_type(4)));

// ---- workspace layout (float offsets) ----
#define XT_OFF    0u          // fp32 256*1024
#define ACT1_OFF  262144u     // f16 196*1024*16
#define ACT2_OFF  1867776u    // f16 144*1024*32
#define ACT3_OFF  4227072u    // f16 100*1024*64
#define W2H_OFF   7503872u    // f16 144*5*32*32
#define W3H_OFF   7872512u    // f16 100*9*64*32
#define P1_OFF    8794112u    // fp32 2*16*3136
#define P2_OFF    8894464u    // fp32 2*32*4608
#define P3_OFF    9189376u    // fp32 2*64*3200
#define FP_OFF    9598976u    // fp32 200*10*1024
#define PRM_OFF   11646976u   // fp32 224
#define BAR_OFF   11647312u   // int region, 7392 zeroed

#define AGENT __HIP_MEMORY_SCOPE_AGENT
#define RLX __ATOMIC_RELAXED

// sc1 = agent-scope write-through stores: data lands at MALL (device coherence
// point) immediately; vmcnt(0) then guarantees device-wide visibility without
// any buffer_wbl2. (R6 lesson: wbl2+inv per barrier forced ALL phase reads to
// MALL and cost ~10us/barrier.)
__device__ __forceinline__ void st4_sc1(float* p, float v) {
    asm volatile("global_store_dword %0, %1, off sc1" :: "v"(p), "v"(v) : "memory");
}
__device__ __forceinline__ void st8_sc1(_Float16* p, f16x4 v) {
    asm volatile("global_store_dwordx2 %0, %1, off sc1" :: "v"(p), "v"(v) : "memory");
}
__device__ __forceinline__ void st16_sc1(_Float16* p, f16x8 v) {
    asm volatile("global_store_dwordx4 %0, %1, off sc1" :: "v"(p), "v"(v) : "memory");
}

// ---------------- prep: weight repack (LDS-staged), x transpose, barrier zero ----------------
__global__ __launch_bounds__(256) void k_prep(const float* __restrict__ x,
                                              const float* __restrict__ W2,
                                              const float* __restrict__ W3,
                                              float* __restrict__ xT,
                                              _Float16* __restrict__ W2h,
                                              _Float16* __restrict__ W3h,
                                              int* __restrict__ bar) {
    __shared__ _Float16 sh[18432];
    __shared__ float tile[16][17];
    int blk = blockIdx.x, tid = threadIdx.x;
    if (blk < 144) {                    // W2 -> W2h [p][t5][o32][k32], pos-pair packed, zero pad
        int p = blk;
        for (int i = tid; i < 5120; i += 256) sh[i] = (_Float16)0.f;
        __syncthreads();
        for (int s = 0; s < 2; s++) {
            int seg = tid + s * 256;    // o*16+c
            int o = seg >> 4, c = seg & 15;
            const float* src = W2 + (size_t)seg * 1296 + p * 9;
#pragma unroll
            for (int pos = 0; pos < 9; pos++) {
                int d = (pos >> 1) * 1024 + o * 32 + (pos & 1) * 16 + c;
                sh[d] = (_Float16)src[pos];
            }
        }
        __syncthreads();
        const int* shi = (const int*)sh;
        int* dst = (int*)(W2h + (size_t)p * 5120);
        for (int i = tid; i < 2560; i += 256) dst[i] = shi[i];
    } else if (blk < 244) {             // W3 -> W3h [p][pos9][o64][c32]
        int p = blk - 144;
        for (int s = 0; s < 8; s++) {
            int seg = tid + s * 256;    // o*32+c
            const float* src = W3 + (size_t)seg * 900 + p * 9;
#pragma unroll
            for (int pos = 0; pos < 9; pos++) sh[pos * 2048 + seg] = (_Float16)src[pos];
        }
        __syncthreads();
        const int* shi = (const int*)sh;
        int* dst = (int*)(W3h + (size_t)p * 18432);
        for (int i = tid; i < 9216; i += 256) dst[i] = shi[i];
    } else if (blk < 1268) {            // x (1024,256) -> xT (256,1024)
        int q = blk - 244;
        int bx = q & 15, by = q >> 4;
        int tx = tid & 15, ty = tid >> 4;
        tile[ty][tx] = x[(by * 16 + ty) * 256 + bx * 16 + tx];
        __syncthreads();
        xT[(bx * 16 + ty) * 1024 + by * 16 + tx] = tile[tx][ty];
    } else {
        for (int i = tid; i < 7392; i += 256) bar[i] = 0;
    }
}

// ---------------- grid barrier: pure signaling (no cache maintenance) ----------------
// All cross-phase data is sc1 write-through; dispatch-start L2 inv (proven by the
// r3 pipeline) kills cross-replay staleness; each address is written once then
// only read. So the barrier needs only: vmcnt-drain -> counters -> flag.
__device__ __forceinline__ void gridbar(int* bar, int k) {
    asm volatile("s_waitcnt vmcnt(0)" ::: "memory");  // every thread drains its sc1 stores
    __syncthreads();
    if (threadIdx.x == 0) {
        int g = blockIdx.x & 7;
        int* base = bar + k * 544;
        int* arrive = base + g * 32;
        int* root = base + 256;          // counter; flag at root[4]
        int* rel = base + 288 + g * 32;
        int prev = __hip_atomic_fetch_add(arrive, 1, RLX, AGENT);
        if (prev == 95) {                // last of group -> bump root
            int r = __hip_atomic_fetch_add(root, 1, RLX, AGENT);
            if (r == 7) __hip_atomic_store(root + 4, 1, RLX, AGENT);
        }
        if (prev == 0) {                 // group leader: poll root flag, then release group
            int guard = 0;
            while (__hip_atomic_load(root + 4, RLX, AGENT) == 0 && ++guard < (1 << 20))
                __builtin_amdgcn_s_sleep(2);
            __hip_atomic_store(rel, 1, RLX, AGENT);
        } else {
            int guard = 0;
            while (__hip_atomic_load(rel, RLX, AGENT) == 0 && ++guard < (1 << 20))
                __builtin_amdgcn_s_sleep(2);
        }
    }
    __syncthreads();
}

__device__ void stats_phase(const float* __restrict__ part, int nwaves,
                            const float* __restrict__ g, const float* __restrict__ be,
                            float* __restrict__ a, float* __restrict__ c,
                            int ch, float invN, float* shf) {
    int tid = threadIdx.x;
    const float* ps = part + (size_t)(2 * ch) * nwaves;
    const float* pq = part + (size_t)(2 * ch + 1) * nwaves;
    float s = 0.f, q = 0.f;
    for (int w = tid; w < nwaves; w += 256) { s += ps[w]; q += pq[w]; }
#pragma unroll
    for (int d = 32; d; d >>= 1) { s += __shfl_down(s, d); q += __shfl_down(q, d); }
    if ((tid & 63) == 0) { shf[tid >> 6] = s; shf[4 + (tid >> 6)] = q; }
    __syncthreads();
    if (tid == 0) {
        s = shf[0] + shf[1] + shf[2] + shf[3];
        q = shf[4] + shf[5] + shf[6] + shf[7];
        float m = s * invN;
        float v = q * invN - m * m;
        float r = rsqrtf(v + EPS);
        float av = g[ch] * r, cv = be[ch] - m * av;
        st4_sc1(a + ch, av);
        st4_sc1(c + ch, cv);
    }
}

// ---------------- the whole net: 8 phases, 7 barriers; batch dim grouped by blk&7 ----------------
__global__ __launch_bounds__(256, 3) void k_fused(
    const float* __restrict__ xT, const float* __restrict__ W1, const float* __restrict__ b1v,
    const float* __restrict__ g1, const float* __restrict__ be1,
    const _Float16* __restrict__ W2h, const float* __restrict__ b2v,
    const float* __restrict__ g2, const float* __restrict__ be2,
    const _Float16* __restrict__ W3h, const float* __restrict__ b3v,
    const float* __restrict__ g3, const float* __restrict__ be3,
    const float* __restrict__ fcW, const float* __restrict__ fcb,
    _Float16* __restrict__ act1h, _Float16* __restrict__ act2h, _Float16* __restrict__ act3h,
    float* __restrict__ p1, float* __restrict__ p2, float* __restrict__ p3,
    float* __restrict__ fpart, float* __restrict__ prm,
    float* __restrict__ out, int* __restrict__ bar) {
    __shared__ float shf[768];
    int blk = blockIdx.x, tid = threadIdx.x;
    int wv = tid >> 6, lane = tid & 63;
    int n = lane & 15, quad = lane >> 4;
    int g = blk & 7, slot = blk >> 3;    // group g's b-range: [g*128, g*128+128)
    int gb = g * 128;

    // ---- P0: LC1 (fp32 VALU), thread = (b 128, oh 2) ----
    {
        int bloc = tid & 127, oh = tid >> 7;
        int b = gb + bloc;
        for (int p = slot; p < 196; p += 96) {
            int i = p / 14, j = p % 14;
            __syncthreads();
            if (tid < 144) { int o = tid / 9, k = tid % 9; shf[tid] = W1[(o * 196 + p) * 9 + k]; }
            if (tid < 16) shf[144 + tid] = b1v[tid * 196 + p];
            __syncthreads();
            float xv[9];
#pragma unroll
            for (int di = 0; di < 3; di++)
#pragma unroll
                for (int dj = 0; dj < 3; dj++)
                    xv[di * 3 + dj] = xT[((i + di) * 16 + (j + dj)) * 1024 + b];
            float accv[8];
#pragma unroll
            for (int e = 0; e < 8; e++) {
                int o = oh * 8 + e;
                float acc = shf[144 + o];
#pragma unroll
                for (int k = 0; k < 9; k++) acc += shf[o * 9 + k] * xv[k];
                accv[e] = acc;
            }
            f16x8 hv;
#pragma unroll
            for (int e = 0; e < 8; e++) hv[e] = (_Float16)accv[e];
            st16_sc1(act1h + ((size_t)(p * 1024 + b)) * 16 + oh * 8, hv);
            int w = (g * 196 + p) * 2 + (wv & 1);
#pragma unroll
            for (int e = 0; e < 8; e++) {
                float s = accv[e], q = accv[e] * accv[e];
#pragma unroll
                for (int d = 32; d; d >>= 1) { s += __shfl_down(s, d); q += __shfl_down(q, d); }
                if (lane == 0) {
                    int ch = oh * 8 + e;
                    st4_sc1(p1 + (2 * ch) * 3136 + w, s);
                    st4_sc1(p1 + (2 * ch + 1) * 3136 + w, q);
                }
            }
        }
    }
    gridbar(bar, 0);
    // ---- P1: stats1 (blocks 752..767) ----
    if (blk >= 752)
        stats_phase(p1, 3136, g1, be1, prm, prm + 16, blk - 752, 1.f / (1024.f * 196.f), shf);
    gridbar(bar, 1);
    // ---- P2: LC2 MFMA; tile = (p, group's 128 b), wave = o32 x b32 ----
    {
        f16x8 a8, c8;
        {
            const float* pa = prm + (quad & 1) * 8;
            f32x4 a0 = *(const f32x4*)pa, a1 = *(const f32x4*)(pa + 4);
            f32x4 c0 = *(const f32x4*)(pa + 16), c1 = *(const f32x4*)(pa + 20);
#pragma unroll
            for (int e = 0; e < 4; e++) {
                a8[e] = (_Float16)a0[e]; a8[4 + e] = (_Float16)a1[e];
                c8[e] = (_Float16)c0[e]; c8[4 + e] = (_Float16)c1[e];
            }
        }
        int bbase = gb + wv * 32;
        for (int p = slot; p < 144; p += 96) {
            int i = p / 12, j = p % 12;
            f32x4 acc[2][2] = {};
#pragma unroll
            for (int tt = 0; tt < 5; tt++) {
                int pos0 = 2 * tt, pos1 = (2 * tt + 1 < 9) ? 2 * tt + 1 : 8;
                int mypos = (quad >> 1) ? pos1 : pos0;
                int ip = (i + mypos / 3) * 14 + (j + mypos % 3);
                f16x8 bfr[2];
#pragma unroll
                for (int nt = 0; nt < 2; nt++) {
                    f16x8 x = *(const f16x8*)(act1h + ((size_t)(ip * 1024 + bbase + nt * 16 + n)) * 16 + (quad & 1) * 8);
#pragma unroll
                    for (int e = 0; e < 8; e++) {
                        _Float16 v = x[e] * a8[e] + c8[e];
                        x[e] = v > (_Float16)0.f ? v : (_Float16)0.f;
                    }
                    bfr[nt] = x;
                }
                f16x8 afr[2];
#pragma unroll
                for (int ot = 0; ot < 2; ot++)
                    afr[ot] = *(const f16x8*)(W2h + ((size_t)((p * 5 + tt) * 32 + ot * 16 + n)) * 32 + quad * 8);
#pragma unroll
                for (int ot = 0; ot < 2; ot++)
#pragma unroll
                    for (int nt = 0; nt < 2; nt++)
                        acc[ot][nt] = __builtin_amdgcn_mfma_f32_16x16x32_f16(afr[ot], bfr[nt], acc[ot][nt], 0, 0, 0);
            }
            float s[8] = {}, q[8] = {};
#pragma unroll
            for (int ot = 0; ot < 2; ot++) {
                float bias[4];
#pragma unroll
                for (int r = 0; r < 4; r++) bias[r] = b2v[(ot * 16 + quad * 4 + r) * 144 + p];
#pragma unroll
                for (int nt = 0; nt < 2; nt++) {
                    int b = bbase + nt * 16 + n;
                    f16x4 st;
#pragma unroll
                    for (int r = 0; r < 4; r++) {
                        float v = acc[ot][nt][r] + bias[r];
                        st[r] = (_Float16)v;
                        s[ot * 4 + r] += v; q[ot * 4 + r] += v * v;
                    }
                    st8_sc1(act2h + ((size_t)(p * 1024 + b)) * 32 + ot * 16 + quad * 4, st);
                }
            }
            int w = (g * 144 + p) * 4 + wv;
#pragma unroll
            for (int u = 0; u < 8; u++) {
                float ss = s[u], qq = q[u];
#pragma unroll
                for (int d = 8; d; d >>= 1) { ss += __shfl_down(ss, d); qq += __shfl_down(qq, d); }
                if (n == 0) {
                    int o = (u >> 2) * 16 + quad * 4 + (u & 3);
                    st4_sc1(p2 + (2 * o) * 4608 + w, ss);
                    st4_sc1(p2 + (2 * o + 1) * 4608 + w, qq);
                }
            }
        }
    }
    gridbar(bar, 2);
    // ---- P3: stats2 (blocks 736..767) ----
    if (blk >= 736)
        stats_phase(p2, 4608, g2, be2, prm + 32, prm + 64, blk - 736, 1.f / (1024.f * 144.f), shf);
    gridbar(bar, 3);
    // ---- P4: LC3 MFMA; tile = (p, group's 128 b), wave = o64 x b32 ----
    {
        f16x8 a8, c8;
        {
            const float* pa = prm + 32 + quad * 8;
            f32x4 a0 = *(const f32x4*)pa, a1 = *(const f32x4*)(pa + 4);
            f32x4 c0 = *(const f32x4*)(pa + 32), c1 = *(const f32x4*)(pa + 36);
#pragma unroll
            for (int e = 0; e < 4; e++) {
                a8[e] = (_Float16)a0[e]; a8[4 + e] = (_Float16)a1[e];
                c8[e] = (_Float16)c0[e]; c8[4 + e] = (_Float16)c1[e];
            }
        }
        int bbase = gb + wv * 32;
        for (int p = slot; p < 100; p += 96) {
            int i = p / 10, j = p % 10;
            f32x4 acc[4][2] = {};
#pragma unroll
            for (int pos = 0; pos < 9; pos++) {
                int ip = (i + pos / 3) * 12 + (j + pos % 3);
                f16x8 bfr[2];
#pragma unroll
                for (int nt = 0; nt < 2; nt++) {
                    f16x8 x = *(const f16x8*)(act2h + ((size_t)(ip * 1024 + bbase + nt * 16 + n)) * 32 + quad * 8);
#pragma unroll
                    for (int e = 0; e < 8; e++) {
                        _Float16 v = x[e] * a8[e] + c8[e];
                        x[e] = v > (_Float16)0.f ? v : (_Float16)0.f;
                    }
                    bfr[nt] = x;
                }
                f16x8 afr[4];
#pragma unroll
                for (int ot = 0; ot < 4; ot++)
                    afr[ot] = *(const f16x8*)(W3h + ((size_t)((p * 9 + pos) * 64 + ot * 16 + n)) * 32 + quad * 8);
#pragma unroll
                for (int ot = 0; ot < 4; ot++)
#pragma unroll
                    for (int nt = 0; nt < 2; nt++)
                        acc[ot][nt] = __builtin_amdgcn_mfma_f32_16x16x32_f16(afr[ot], bfr[nt], acc[ot][nt], 0, 0, 0);
            }
            float s[16] = {}, q[16] = {};
#pragma unroll
            for (int ot = 0; ot < 4; ot++) {
                float bias[4];
#pragma unroll
                for (int r = 0; r < 4; r++) bias[r] = b3v[(ot * 16 + quad * 4 + r) * 100 + p];
#pragma unroll
                for (int nt = 0; nt < 2; nt++) {
                    int b = bbase + nt * 16 + n;
                    f16x4 st;
#pragma unroll
                    for (int r = 0; r < 4; r++) {
                        float v = acc[ot][nt][r] + bias[r];
                        st[r] = (_Float16)v;
                        s[ot * 4 + r] += v; q[ot * 4 + r] += v * v;
                    }
                    st8_sc1(act3h + ((size_t)(p * 1024 + b)) * 64 + ot * 16 + quad * 4, st);
                }
            }
            int w = (g * 100 + p) * 4 + wv;
#pragma unroll
            for (int u = 0; u < 16; u++) {
                float ss = s[u], qq = q[u];
#pragma unroll
                for (int d = 8; d; d >>= 1) { ss += __shfl_down(ss, d); qq += __shfl_down(qq, d); }
                if (n == 0) {
                    int o = (u >> 2) * 16 + quad * 4 + (u & 3);
                    st4_sc1(p3 + (2 * o) * 3200 + w, ss);
                    st4_sc1(p3 + (2 * o + 1) * 3200 + w, qq);
                }
            }
        }
    }
    gridbar(bar, 4);
    // ---- P5: stats3 (blocks 704..767) ----
    if (blk >= 704)
        stats_phase(p3, 3200, g3, be3, prm + 96, prm + 160, blk - 704, 1.f / (1024.f * 100.f), shf);
    gridbar(bar, 5);
    // ---- P6: FC (tanh(BN3) @ fcW^T); tile = (p, group's 128 b x 2 oh) ----
    {
        int bloc = tid & 127, oh = tid >> 7;
        int b = gb + bloc, ob = oh * 32;
        for (int p = slot; p < 100; p += 96) {
            __syncthreads();
            for (int idx = tid; idx < 640; idx += 256) {
                int o = idx / 10, jj = idx % 10;
                shf[idx] = fcW[jj * 6400 + o * 100 + p];
            }
            if (tid < 64) { shf[640 + tid] = prm[96 + tid]; shf[704 + tid] = prm[160 + tid]; }
            __syncthreads();
            float acc[10];
#pragma unroll
            for (int jj = 0; jj < 10; jj++) acc[jj] = 0.f;
            const _Float16* src = act3h + ((size_t)(p * 1024 + b)) * 64 + ob;
#pragma unroll
            for (int o8 = 0; o8 < 4; o8++) {
                f16x8 xv = *(const f16x8*)(src + o8 * 8);
#pragma unroll
                for (int e = 0; e < 8; e++) {
                    int o = ob + o8 * 8 + e;
                    float v = fmaf(shf[640 + o], (float)xv[e], shf[704 + o]);
                    float e2 = __expf(2.f * v);
                    v = 1.f - 2.f / (e2 + 1.f);   // tanh, safe at +/-inf
#pragma unroll
                    for (int jj = 0; jj < 10; jj++) acc[jj] = fmaf(shf[o * 10 + jj], v, acc[jj]);
                }
            }
#pragma unroll
            for (int jj = 0; jj < 10; jj++)
                st4_sc1(fpart + ((size_t)(oh * 100 + p) * 10 + jj) * 1024 + b, acc[jj]);
        }
    }
    gridbar(bar, 6);
    // ---- P7: reduce fc partials + bias -> out (5 blocks per group, b-local) ----
    if (slot < 5) {
        int il = slot * 256 + tid;       // < 1280 = 10 jj x 128 b
        int jj = il >> 7, b = gb + (il & 127);
        float acc = fcb[jj];
        for (int ch = 0; ch < 200; ch++) acc += fpart[((size_t)ch * 10 + jj) * 1024 + b];
        out[b * 10 + jj] = acc;
    }
}

extern "C" void kernel_launch(void* const* d_in, const int* in_sizes, int n_in,
                              void* d_out, int out_size, void* d_ws, size_t ws_size,
                              hipStream_t stream) {
    const float* x   = (const float*)d_in[0];
    const float* W1  = (const float*)d_in[1];
    const float* b1  = (const float*)d_in[2];
    const float* g1  = (const float*)d_in[3];
    const float* be1 = (const float*)d_in[4];
    const float* W2  = (const float*)d_in[5];
    const float* b2  = (const float*)d_in[6];
    const float* g2  = (const float*)d_in[7];
    const float* be2 = (const float*)d_in[8];
    const float* W3  = (const float*)d_in[9];
    const float* b3  = (const float*)d_in[10];
    const float* g3  = (const float*)d_in[11];
    const float* be3 = (const float*)d_in[12];
    const float* fcW = (const float*)d_in[13];
    const float* fcb = (const float*)d_in[14];
    float* out = (float*)d_out;
    float* ws = (float*)d_ws;

    float* xT       = ws + XT_OFF;
    _Float16* act1h = (_Float16*)(ws + ACT1_OFF);
    _Float16* act2h = (_Float16*)(ws + ACT2_OFF);
    _Float16* act3h = (_Float16*)(ws + ACT3_OFF);
    _Float16* W2h   = (_Float16*)(ws + W2H_OFF);
    _Float16* W3h   = (_Float16*)(ws + W3H_OFF);
    float* p1   = ws + P1_OFF;
    float* p2   = ws + P2_OFF;
    float* p3   = ws + P3_OFF;
    float* fp   = ws + FP_OFF;
    float* prm  = ws + PRM_OFF;
    int* bar    = (int*)(ws + BAR_OFF);

    k_prep<<<1269, 256, 0, stream>>>(x, W2, W3, xT, W2h, W3h, bar);
    k_fused<<<NBLK, 256, 0, stream>>>(xT, W1, b1, g1, be1, W2h, b2, g2, be2,
                                      W3h, b3, g3, be3, fcW, fcb,
                                      act1h, act2h, act3h, p1, p2, p3, fp, prm, out, bar);
}

// Round 8
// 207.472 us; speedup vs baseline: 4.3255x; 1.0148x over previous
//
#include <hip/hip_runtime.h>

#define EPS 1e-5f
#define NBLK 768

typedef _Float16 f16x8 __attribute__((ext_vector_type(8)));
typedef _Float16 f16x4 __attribute__((ext_vector_type(4)));
typedef float f32x4 __attribute__((ext_vector_type(4)));

// ---- workspace layout (float offsets) ----
#define XT_OFF    0u          // fp32 256*1024
#define ACT1_OFF  262144u     // f16 196*1024*16 (sc1 write-through, full lines)
#define ACT2_OFF  1867776u    // f16 144*1024*32 (write-back, XCD-local)
#define ACT3_OFF  4227072u    // f16 100*1024*64 (write-back, XCD-local)
#define W2H_OFF   7503872u    // f16 144*5*32*32 (sc1)
#define W3H_OFF   7872512u    // f16 100*9*64*32 (sc1)
#define P1_OFF    8794112u    // fp32 1568*32 packed per-tile stats (sc1 lines)
#define P2_OFF    8844288u    // fp32 1152*256
#define P3_OFF    9139200u    // fp32 800*512
#define FP_OFF    9548800u    // fp32 200*10*1024 (write-back, XCD-local)
#define PRM_OFF   11596800u   // fp32 224 (sc1; 128B-line partitioned by phase)
#define BAR_OFF   11597056u   // int region; 7 barriers*544 + reg counters at 3808

#define AGENT __HIP_MEMORY_SCOPE_AGENT
#define RLX __ATOMIC_RELAXED
#define REG_OFF 3808

__device__ __forceinline__ void st4_sc1(float* p, float v) {
    asm volatile("global_store_dword %0, %1, off sc1" :: "v"(p), "v"(v) : "memory");
}
__device__ __forceinline__ void sti_sc1(int* p, int v) {
    asm volatile("global_store_dword %0, %1, off sc1" :: "v"(p), "v"(v) : "memory");
}
__device__ __forceinline__ void st16_sc1(_Float16* p, f16x8 v) {
    asm volatile("global_store_dwordx4 %0, %1, off sc1" :: "v"(p), "v"(v) : "memory");
}

// ---------------- prep: x transpose + barrier zero ----------------
__global__ __launch_bounds__(256) void k_prep(const float* __restrict__ x,
                                              float* __restrict__ xT,
                                              int* __restrict__ bar) {
    __shared__ float tile[16][17];
    int blk = blockIdx.x, tid = threadIdx.x;
    if (blk < 1024) {                   // x (1024,256) -> xT (256,1024)
        int bx = blk & 15, by = blk >> 4;
        int tx = tid & 15, ty = tid >> 4;
        tile[ty][tx] = x[(by * 16 + ty) * 256 + bx * 16 + tx];
        __syncthreads();
        xT[(bx * 16 + ty) * 1024 + by * 16 + tx] = tile[tx][ty];
    } else {
        for (int i = tid; i < 4096; i += 256) bar[i] = 0;
    }
}

// ---------------- grid barrier: pure signaling (r7, proven) ----------------
__device__ __forceinline__ void gridbar(int* bar, int k) {
    asm volatile("s_waitcnt vmcnt(0)" ::: "memory");
    __syncthreads();
    if (threadIdx.x == 0) {
        int g = blockIdx.x & 7;
        int* base = bar + k * 544;
        int* arrive = base + g * 32;
        int* root = base + 256;
        int* rel = base + 288 + g * 32;
        int prev = __hip_atomic_fetch_add(arrive, 1, RLX, AGENT);
        if (prev == 95) {
            int r = __hip_atomic_fetch_add(root, 1, RLX, AGENT);
            if (r == 7) __hip_atomic_store(root + 4, 1, RLX, AGENT);
        }
        if (prev == 0) {
            int guard = 0;
            while (__hip_atomic_load(root + 4, RLX, AGENT) == 0 && ++guard < (1 << 20))
                __builtin_amdgcn_s_sleep(2);
            __hip_atomic_store(rel, 1, RLX, AGENT);
        } else {
            int guard = 0;
            while (__hip_atomic_load(rel, RLX, AGENT) == 0 && ++guard < (1 << 20))
                __builtin_amdgcn_s_sleep(2);
        }
    }
    __syncthreads();
}

// part[w][2*CH] packed lines; s at w*stride+ch*2, q at +1
__device__ void stats_phase(const float* __restrict__ part, int count, int stride,
                            const float* __restrict__ g, const float* __restrict__ be,
                            float* __restrict__ a, float* __restrict__ c,
                            int ch, float invN, float* shf) {
    int tid = threadIdx.x;
    float s = 0.f, q = 0.f;
    for (int w = tid; w < count; w += 256) {
        const float* p = part + (size_t)w * stride + ch * 2;
        s += p[0]; q += p[1];
    }
#pragma unroll
    for (int d = 32; d; d >>= 1) { s += __shfl_down(s, d); q += __shfl_down(q, d); }
    if ((tid & 63) == 0) { shf[tid >> 6] = s; shf[4 + (tid >> 6)] = q; }
    __syncthreads();
    if (tid == 0) {
        s = shf[0] + shf[1] + shf[2] + shf[3];
        q = shf[4] + shf[5] + shf[6] + shf[7];
        float m = s * invN;
        float v = q * invN - m * m;
        float r = rsqrtf(v + EPS);
        float av = g[ch] * r, cv = be[ch] - m * av;
        st4_sc1(a + ch, av);
        st4_sc1(c + ch, cv);
    }
}

// ---------------- the whole net ----------------
__global__ __launch_bounds__(256, 3) void k_fused(
    const float* __restrict__ xT, const float* __restrict__ W1, const float* __restrict__ b1v,
    const float* __restrict__ g1, const float* __restrict__ be1,
    const float* __restrict__ W2, _Float16* __restrict__ W2h, const float* __restrict__ b2v,
    const float* __restrict__ g2, const float* __restrict__ be2,
    const float* __restrict__ W3, _Float16* __restrict__ W3h, const float* __restrict__ b3v,
    const float* __restrict__ g3, const float* __restrict__ be3,
    const float* __restrict__ fcW, const float* __restrict__ fcb,
    _Float16* __restrict__ act1h, _Float16* __restrict__ act2h, _Float16* __restrict__ act3h,
    float* __restrict__ p1, float* __restrict__ p2, float* __restrict__ p3,
    float* __restrict__ fpart, float* __restrict__ prm,
    float* __restrict__ out, int* __restrict__ bar) {
    __shared__ short sh16[18432];       // 36 KB multi-purpose
    __shared__ int meta[4];             // [0]=rank [1]=xcnt [2]=myxcd
    float* shf = (float*)sh16;
    int blk = blockIdx.x, tid = threadIdx.x;
    int wv = tid >> 6, lane = tid & 63;
    int n = lane & 15, quad = lane >> 4;

    // ---- registration: physical XCD + rank within it ----
    if (tid == 0) {
        int x;
        asm volatile("s_getreg_b32 %0, hwreg(HW_REG_XCC_ID, 0, 4)" : "=s"(x));
        x &= 7;
        meta[2] = x;
        meta[0] = __hip_atomic_fetch_add(bar + REG_OFF + x * 32, 1, RLX, AGENT);
    }

    // ---- P0: weight repack (blocks 0..243) | LC1 (blocks 244..767) ----
    if (blk < 144) {                    // W2 -> W2h [p][t5][o32][k32]
        _Float16* sh = (_Float16*)sh16;
        int p = blk;
        for (int i = tid; i < 5120; i += 256) sh[i] = (_Float16)0.f;
        __syncthreads();
        for (int s = 0; s < 2; s++) {
            int seg = tid + s * 256;
            int o = seg >> 4, c = seg & 15;
            const float* src = W2 + (size_t)seg * 1296 + p * 9;
#pragma unroll
            for (int pos = 0; pos < 9; pos++)
                sh[(pos >> 1) * 1024 + o * 32 + (pos & 1) * 16 + c] = (_Float16)src[pos];
        }
        __syncthreads();
        const int* shi = (const int*)sh16;
        int* dst = (int*)(W2h + (size_t)p * 5120);
        for (int i = tid; i < 2560; i += 256) sti_sc1(dst + i, shi[i]);
    } else if (blk < 244) {             // W3 -> W3h [p][pos9][o64][c32]
        _Float16* sh = (_Float16*)sh16;
        int p = blk - 144;
        for (int s = 0; s < 8; s++) {
            int seg = tid + s * 256;
            const float* src = W3 + (size_t)seg * 900 + p * 9;
#pragma unroll
            for (int pos = 0; pos < 9; pos++) sh[pos * 2048 + seg] = (_Float16)src[pos];
        }
        __syncthreads();
        const int* shi = (const int*)sh16;
        int* dst = (int*)(W3h + (size_t)p * 18432);
        for (int i = tid; i < 9216; i += 256) sti_sc1(dst + i, shi[i]);
    } else {                            // LC1 units u=(g8,p196), 524 blocks
        int bloc = tid & 127, oh = tid >> 7;
        for (int u = blk - 244; u < 1568; u += 524) {
            int g = u & 7, p = u >> 3;
            int i = p / 14, j = p % 14;
            int b = g * 128 + bloc;
            __syncthreads();
            if (tid < 144) { int o = tid / 9, k = tid % 9; shf[tid] = W1[(o * 196 + p) * 9 + k]; }
            if (tid < 16) shf[144 + tid] = b1v[tid * 196 + p];
            __syncthreads();
            float xv[9];
#pragma unroll
            for (int di = 0; di < 3; di++)
#pragma unroll
                for (int dj = 0; dj < 3; dj++)
                    xv[di * 3 + dj] = xT[((i + di) * 16 + (j + dj)) * 1024 + b];
            float accv[8];
#pragma unroll
            for (int e = 0; e < 8; e++) {
                int o = oh * 8 + e;
                float acc = shf[144 + o];
#pragma unroll
                for (int k = 0; k < 9; k++) acc += shf[o * 9 + k] * xv[k];
                accv[e] = acc;
            }
            f16x8 hv;
#pragma unroll
            for (int e = 0; e < 8; e++) hv[e] = (_Float16)accv[e];
            st16_sc1(act1h + ((size_t)(p * 1024 + b)) * 16 + oh * 8, hv);
            // pack per-tile stats: wave-reduce -> LDS -> 128B line
#pragma unroll
            for (int e = 0; e < 8; e++) {
                float s = accv[e], q = accv[e] * accv[e];
#pragma unroll
                for (int d = 32; d; d >>= 1) { s += __shfl_down(s, d); q += __shfl_down(q, d); }
                if (lane == 0) { shf[160 + wv * 8 + e] = s; shf[192 + wv * 8 + e] = q; }
            }
            __syncthreads();
            if (tid < 16) {
                int ohh = tid >> 3, e = tid & 7;
                float s = shf[160 + (ohh * 2) * 8 + e] + shf[160 + (ohh * 2 + 1) * 8 + e];
                float q = shf[192 + (ohh * 2) * 8 + e] + shf[192 + (ohh * 2 + 1) * 8 + e];
                shf[224 + tid * 2] = s; shf[225 + tid * 2] = q;
            }
            __syncthreads();
            if (tid < 32) st4_sc1(p1 + (size_t)u * 32 + tid, shf[224 + tid]);
        }
    }
    gridbar(bar, 0);
    if (tid == 0) meta[1] = __hip_atomic_load(bar + REG_OFF + meta[2] * 32, RLX, AGENT);
    // ---- P1: stats1 ----
    if (blk >= 752)
        stats_phase(p1, 1568, 32, g1, be1, prm, prm + 16, blk - 752, 1.f / (1024.f * 196.f), shf);
    gridbar(bar, 1);
    int rank = meta[0], xcnt = meta[1], myx = meta[2];
    int gb = myx * 128;
    // ---- P2: LC2 MFMA, XCD-local b-slice ----
    {
        f16x8 a8, c8;
        {
            const float* pa = prm + (quad & 1) * 8;
            f32x4 a0 = *(const f32x4*)pa, a1 = *(const f32x4*)(pa + 4);
            f32x4 c0 = *(const f32x4*)(pa + 16), c1 = *(const f32x4*)(pa + 20);
#pragma unroll
            for (int e = 0; e < 4; e++) {
                a8[e] = (_Float16)a0[e]; a8[4 + e] = (_Float16)a1[e];
                c8[e] = (_Float16)c0[e]; c8[4 + e] = (_Float16)c1[e];
            }
        }
        int bbase = gb + wv * 32;
        for (int p = rank; p < 144; p += xcnt) {
            int i = p / 12, j = p % 12;
            f32x4 acc[2][2] = {};
#pragma unroll
            for (int tt = 0; tt < 5; tt++) {
                int pos0 = 2 * tt, pos1 = (2 * tt + 1 < 9) ? 2 * tt + 1 : 8;
                int mypos = (quad >> 1) ? pos1 : pos0;
                int ip = (i + mypos / 3) * 14 + (j + mypos % 3);
                f16x8 bfr[2];
#pragma unroll
                for (int nt = 0; nt < 2; nt++) {
                    f16x8 x = *(const f16x8*)(act1h + ((size_t)(ip * 1024 + bbase + nt * 16 + n)) * 16 + (quad & 1) * 8);
#pragma unroll
                    for (int e = 0; e < 8; e++) {
                        _Float16 v = x[e] * a8[e] + c8[e];
                        x[e] = v > (_Float16)0.f ? v : (_Float16)0.f;
                    }
                    bfr[nt] = x;
                }
                f16x8 afr[2];
#pragma unroll
                for (int ot = 0; ot < 2; ot++)
                    afr[ot] = *(const f16x8*)(W2h + ((size_t)((p * 5 + tt) * 32 + ot * 16 + n)) * 32 + quad * 8);
#pragma unroll
                for (int ot = 0; ot < 2; ot++)
#pragma unroll
                    for (int nt = 0; nt < 2; nt++)
                        acc[ot][nt] = __builtin_amdgcn_mfma_f32_16x16x32_f16(afr[ot], bfr[nt], acc[ot][nt], 0, 0, 0);
            }
            float s[8] = {}, q[8] = {};
#pragma unroll
            for (int ot = 0; ot < 2; ot++) {
                float bias[4];
#pragma unroll
                for (int r = 0; r < 4; r++) bias[r] = b2v[(ot * 16 + quad * 4 + r) * 144 + p];
#pragma unroll
                for (int nt = 0; nt < 2; nt++) {
                    int b = bbase + nt * 16 + n;
                    f16x4 st;
#pragma unroll
                    for (int r = 0; r < 4; r++) {
                        float v = acc[ot][nt][r] + bias[r];
                        st[r] = (_Float16)v;
                        s[ot * 4 + r] += v; q[ot * 4 + r] += v * v;
                    }
                    *(f16x4*)(act2h + ((size_t)(p * 1024 + b)) * 32 + ot * 16 + quad * 4) = st;  // write-back, L2-local
                }
            }
            __syncthreads();
#pragma unroll
            for (int u = 0; u < 8; u++) {
                float ss = s[u], qq = q[u];
#pragma unroll
                for (int d = 8; d; d >>= 1) { ss += __shfl_down(ss, d); qq += __shfl_down(qq, d); }
                if (n == 0) {
                    int o = (u >> 2) * 16 + quad * 4 + (u & 3);
                    shf[wv * 64 + o * 2] = ss; shf[wv * 64 + o * 2 + 1] = qq;
                }
            }
            __syncthreads();
            int t = myx * 144 + p;
            st4_sc1(p2 + (size_t)t * 256 + tid, shf[tid]);
        }
    }
    gridbar(bar, 2);
    // ---- P3: stats2 ----
    if (blk >= 736)
        stats_phase(p2, 4608, 64, g2, be2, prm + 32, prm + 64, blk - 736, 1.f / (1024.f * 144.f), shf);
    gridbar(bar, 3);
    // ---- P4: LC3 MFMA, XCD-local ----
    {
        f16x8 a8, c8;
        {
            const float* pa = prm + 32 + quad * 8;
            f32x4 a0 = *(const f32x4*)pa, a1 = *(const f32x4*)(pa + 4);
            f32x4 c0 = *(const f32x4*)(pa + 32), c1 = *(const f32x4*)(pa + 36);
#pragma unroll
            for (int e = 0; e < 4; e++) {
                a8[e] = (_Float16)a0[e]; a8[4 + e] = (_Float16)a1[e];
                c8[e] = (_Float16)c0[e]; c8[4 + e] = (_Float16)c1[e];
            }
        }
        int bbase = gb + wv * 32;
        for (int p = rank; p < 100; p += xcnt) {
            int i = p / 10, j = p % 10;
            f32x4 acc[4][2] = {};
#pragma unroll
            for (int pos = 0; pos < 9; pos++) {
                int ip = (i + pos / 3) * 12 + (j + pos % 3);
                f16x8 bfr[2];
#pragma unroll
                for (int nt = 0; nt < 2; nt++) {
                    f16x8 x = *(const f16x8*)(act2h + ((size_t)(ip * 1024 + bbase + nt * 16 + n)) * 32 + quad * 8);
#pragma unroll
                    for (int e = 0; e < 8; e++) {
                        _Float16 v = x[e] * a8[e] + c8[e];
                        x[e] = v > (_Float16)0.f ? v : (_Float16)0.f;
                    }
                    bfr[nt] = x;
                }
                f16x8 afr[4];
#pragma unroll
                for (int ot = 0; ot < 4; ot++)
                    afr[ot] = *(const f16x8*)(W3h + ((size_t)((p * 9 + pos) * 64 + ot * 16 + n)) * 32 + quad * 8);
#pragma unroll
                for (int ot = 0; ot < 4; ot++)
#pragma unroll
                    for (int nt = 0; nt < 2; nt++)
                        acc[ot][nt] = __builtin_amdgcn_mfma_f32_16x16x32_f16(afr[ot], bfr[nt], acc[ot][nt], 0, 0, 0);
            }
            float s[16] = {}, q[16] = {};
#pragma unroll
            for (int ot = 0; ot < 4; ot++) {
                float bias[4];
#pragma unroll
                for (int r = 0; r < 4; r++) bias[r] = b3v[(ot * 16 + quad * 4 + r) * 100 + p];
#pragma unroll
                for (int nt = 0; nt < 2; nt++) {
                    int b = bbase + nt * 16 + n;
                    f16x4 st;
#pragma unroll
                    for (int r = 0; r < 4; r++) {
                        float v = acc[ot][nt][r] + bias[r];
                        st[r] = (_Float16)v;
                        s[ot * 4 + r] += v; q[ot * 4 + r] += v * v;
                    }
                    *(f16x4*)(act3h + ((size_t)(p * 1024 + b)) * 64 + ot * 16 + quad * 4) = st;  // write-back
                }
            }
            __syncthreads();
#pragma unroll
            for (int u = 0; u < 16; u++) {
                float ss = s[u], qq = q[u];
#pragma unroll
                for (int d = 8; d; d >>= 1) { ss += __shfl_down(ss, d); qq += __shfl_down(qq, d); }
                if (n == 0) {
                    int o = (u >> 2) * 16 + quad * 4 + (u & 3);
                    shf[wv * 128 + o * 2] = ss; shf[wv * 128 + o * 2 + 1] = qq;
                }
            }
            __syncthreads();
            int t = myx * 100 + p;
            st4_sc1(p3 + (size_t)t * 512 + tid, shf[tid]);
            st4_sc1(p3 + (size_t)t * 512 + 256 + tid, shf[256 + tid]);
        }
    }
    gridbar(bar, 4);
    // ---- P5: stats3 ----
    if (blk >= 704)
        stats_phase(p3, 3200, 128, g3, be3, prm + 96, prm + 160, blk - 704, 1.f / (1024.f * 100.f), shf);
    gridbar(bar, 5);
    // ---- P6: FC (tanh(BN3) @ fcW^T) -> fpart, XCD-local ----
    {
        int bloc = tid & 127, oh = tid >> 7;
        int b = gb + bloc, ob = oh * 32;
        for (int p = rank; p < 100; p += xcnt) {
            __syncthreads();
            for (int idx = tid; idx < 640; idx += 256) {
                int o = idx / 10, jj = idx % 10;
                shf[idx] = fcW[jj * 6400 + o * 100 + p];
            }
            if (tid < 64) { shf[640 + tid] = prm[96 + tid]; shf[704 + tid] = prm[160 + tid]; }
            __syncthreads();
            float acc[10];
#pragma unroll
            for (int jj = 0; jj < 10; jj++) acc[jj] = 0.f;
            const _Float16* src = act3h + ((size_t)(p * 1024 + b)) * 64 + ob;
#pragma unroll
            for (int o8 = 0; o8 < 4; o8++) {
                f16x8 xv = *(const f16x8*)(src + o8 * 8);
#pragma unroll
                for (int e = 0; e < 8; e++) {
                    int o = ob + o8 * 8 + e;
                    float v = fmaf(shf[640 + o], (float)xv[e], shf[704 + o]);
                    float e2 = __expf(2.f * v);
                    v = 1.f - 2.f / (e2 + 1.f);   // tanh, safe at +/-inf
#pragma unroll
                    for (int jj = 0; jj < 10; jj++) acc[jj] = fmaf(shf[o * 10 + jj], v, acc[jj]);
                }
            }
#pragma unroll
            for (int jj = 0; jj < 10; jj++)
                fpart[((size_t)(oh * 100 + p) * 10 + jj) * 1024 + b] = acc[jj];  // write-back, L2-local
        }
    }
    gridbar(bar, 6);
    // ---- P7: reduce fpart + bias -> out (ranks 0..4 per XCD, b-local) ----
    if (rank < 5) {
        int il = rank * 256 + tid;       // < 1280 = 10 jj x 128 b
        int jj = il >> 7, b = gb + (il & 127);
        float acc = fcb[jj];
        for (int ch = 0; ch < 200; ch++) acc += fpart[((size_t)ch * 10 + jj) * 1024 + b];
        out[b * 10 + jj] = acc;
    }
}

extern "C" void kernel_launch(void* const* d_in, const int* in_sizes, int n_in,
                              void* d_out, int out_size, void* d_ws, size_t ws_size,
                              hipStream_t stream) {
    const float* x   = (const float*)d_in[0];
    const float* W1  = (const float*)d_in[1];
    const float* b1  = (const float*)d_in[2];
    const float* g1  = (const float*)d_in[3];
    const float* be1 = (const float*)d_in[4];
    const float* W2  = (const float*)d_in[5];
    const float* b2  = (const float*)d_in[6];
    const float* g2  = (const float*)d_in[7];
    const float* be2 = (const float*)d_in[8];
    const float* W3  = (const float*)d_in[9];
    const float* b3  = (const float*)d_in[10];
    const float* g3  = (const float*)d_in[11];
    const float* be3 = (const float*)d_in[12];
    const float* fcW = (const float*)d_in[13];
    const float* fcb = (const float*)d_in[14];
    float* out = (float*)d_out;
    float* ws = (float*)d_ws;

    float* xT       = ws + XT_OFF;
    _Float16* act1h = (_Float16*)(ws + ACT1_OFF);
    _Float16* act2h = (_Float16*)(ws + ACT2_OFF);
    _Float16* act3h = (_Float16*)(ws + ACT3_OFF);
    _Float16* W2h   = (_Float16*)(ws + W2H_OFF);
    _Float16* W3h   = (_Float16*)(ws + W3H_OFF);
    float* p1   = ws + P1_OFF;
    float* p2   = ws + P2_OFF;
    float* p3   = ws + P3_OFF;
    float* fp   = ws + FP_OFF;
    float* prm  = ws + PRM_OFF;
    int* bar    = (int*)(ws + BAR_OFF);

    k_prep<<<1025, 256, 0, stream>>>(x, xT, bar);
    k_fused<<<NBLK, 256, 0, stream>>>(xT, W1, b1, g1, be1, W2, W2h, b2, g2, be2,
                                      W3, W3h, b3, g3, be3, fcW, fcb,
                                      act1h, act2h, act3h, p1, p2, p3, fp, prm, out, bar);
}